// Round 9
// baseline (4370.624 us; speedup 1.0000x reference)
//
#include <hip/hip_runtime.h>
#include <math.h>

// ODE-RNN forward: B=1024, T=100, D=32, H=256, MID=50 (padded 64), RK4x4.
// Round 9: 4 rows/block as two pairs (P,Q), software-pipelined across the
// A/B thread halves so BOTH halves compute every phase (A: L1(pair X) while
// B: L2(pair Y)). No waves_per_eu attr -> 256-VGPR cap, no spill (R8: wpe(4)
// capped at 64 VGPR and spilled 38MB). DPP butterflies verified in R8.

#define NT 512

// ---- ws layout (float4 units) ----
#define WF_WCAT 0        // [(c*9+gg)][512 tid] f4 : RNN concat weights
#define WF_L1   18432    // [(c*32+jj)][64 low] f4 : mu-l1
#define WF_SG   26624    // [(c*64+kq)][64 cqB] f4 : sigma-l1

// ---- LDS layout (f4 offsets) ----
#define F4_YCP  0        // [2 rows][64]
#define F4_YCQ  128
#define F4_MIDP 256      // [2 rows][16]
#define F4_MIDQ 288
#define F4_HL   320      // [2 parity][4 rows][64]
#define F4_X    832      // [2 parity][4 rows][8]
#define F4_L1O  896      // [4 rows][32]
#define F4_SG   1024     // [4 rows][64]
#define SM_L1B  5120     // float offsets from here
#define SM_SB1  5248
#define SM_MUW  5504
#define SM_SW2  5632
#define SM_SCL  5888     // [2 parity][4 rows]
#define SM_TOTF 5896

__device__ __forceinline__ float fma4(float acc, float4 y, float4 w) {
  acc = fmaf(y.x, w.x, acc); acc = fmaf(y.y, w.y, acc);
  acc = fmaf(y.z, w.z, acc); acc = fmaf(y.w, w.w, acc);
  return acc;
}
__device__ __forceinline__ float4 add4(float4 a, float4 b) {
  return make_float4(a.x + b.x, a.y + b.y, a.z + b.z, a.w + b.w);
}
__device__ __forceinline__ float4 axpy4(float a, float4 xv, float4 yv) {
  return make_float4(fmaf(a, xv.x, yv.x), fmaf(a, xv.y, yv.y),
                     fmaf(a, xv.z, yv.z), fmaf(a, xv.w, yv.w));
}
__device__ __forceinline__ float4 muls4(float4 v, float s) {
  return make_float4(v.x * s, v.y * s, v.z * s, v.w * s);
}
__device__ __forceinline__ float tfast(float x) {
  float ax = fabsf(x);
  float e  = __expf(-2.f * ax);
  float t  = (1.f - e) * __builtin_amdgcn_rcpf(1.f + e);
  return copysignf(t, x);
}
__device__ __forceinline__ float4 tfast4(float4 v) {
  return make_float4(tfast(v.x), tfast(v.y), tfast(v.z), tfast(v.w));
}
// DPP butterfly adds (verified R8): after redN every lane of each aligned
// N-lane group holds the group sum. Pure VALU.
template <int CTRL>
__device__ __forceinline__ float dpp_add(float v) {
  int s = __builtin_amdgcn_update_dpp(0, __float_as_int(v), CTRL, 0xF, 0xF, true);
  return v + __int_as_float(s);
}
__device__ __forceinline__ float red2(float v)  { return dpp_add<0xB1>(v); }
__device__ __forceinline__ float red4(float v)  { return dpp_add<0x4E>(dpp_add<0xB1>(v)); }
__device__ __forceinline__ float red8(float v)  {
  return dpp_add<0xB1>(dpp_add<0x4E>(dpp_add<0x141>(v)));
}
__device__ __forceinline__ float red16(float v) {
  return dpp_add<0xB1>(dpp_add<0x4E>(dpp_add<0x141>(dpp_add<0x140>(v))));
}

__global__ void prep_w(const float* __restrict__ Wih, const float* __restrict__ Whh,
                       const float* __restrict__ l1w, const float* __restrict__ sw1,
                       float* __restrict__ ws) {
  int i = blockIdx.x * 256 + threadIdx.x;
  if (i < 73728) {                       // wcat (unchanged from R8)
    int fi = i >> 2, comp = i & 3;
    int j = fi >> 9, tw = fi & 511;
    int c = j / 9, gg = j - c * 9;
    int cq = tw >> 3, kc = tw & 7;
    int k = 36 * kc + 4 * gg + comp, col = 4 * cq + c;
    ws[i] = (k < 32) ? Wih[col * 32 + k] : Whh[col * 256 + (k - 32)];
  } else if (i < 106496) {               // l1: (c*32+jj)*64 + low
    int t = i - 73728;
    int fi = t >> 2, comp = t & 3;
    int low = fi & 63, rest = fi >> 6;
    int c = rest >> 5, jj = rest & 31;
    int cqH = low >> 1, kcH = low & 1;
    int col = 4 * cqH + c, k = 4 * (32 * kcH + jj) + comp;
    ws[73728 + t] = l1w[col * 256 + k];
  } else {                               // sig: (c*64+kq)*64 + cqB
    int t = i - 106496;
    int fi = t >> 2, comp = t & 3;
    int cqB = fi & 63, rest = fi >> 6;
    int c = rest >> 6, kq = rest & 63;
    int col = 4 * cqB + c, k = 4 * kq + comp;
    ws[106496 + t] = sw1[col * 256 + k];
  }
}

// RNN for 4 rows, all 512 threads: (cq 64, kc 8), 4 cols x 4 rows.
__device__ __forceinline__ void rnn_phase4(int tid, int pOld,
                                           const float4* __restrict__ wc4,
                                           float4* smf4, float4 bcR) {
  const int cq = tid >> 3, kc = tid & 7;
  float a00=0,a01=0,a02=0,a03=0, a10=0,a11=0,a12=0,a13=0;
  float a20=0,a21=0,a22=0,a23=0, a30=0,a31=0,a32=0,a33=0;
#pragma unroll 1
  for (int gg = 0; gg < 9; ++gg) {
    int g = kc * 9 + gg;
    float4 w0 = wc4[(0 * 9 + gg) * 512 + tid];
    float4 w1 = wc4[(1 * 9 + gg) * 512 + tid];
    float4 w2 = wc4[(2 * 9 + gg) * 512 + tid];
    float4 w3 = wc4[(3 * 9 + gg) * 512 + tid];
    float4 y0, y1, y2, y3;
    if (g < 8) {
      const int xb = F4_X + pOld * 32;
      y0 = smf4[xb + g]; y1 = smf4[xb + 8 + g];
      y2 = smf4[xb + 16 + g]; y3 = smf4[xb + 24 + g];
    } else {
      const int hb = F4_HL + pOld * 256 + (g - 8);
      y0 = smf4[hb]; y1 = smf4[hb + 64];
      y2 = smf4[hb + 128]; y3 = smf4[hb + 192];
    }
    a00=fma4(a00,y0,w0); a01=fma4(a01,y0,w1); a02=fma4(a02,y0,w2); a03=fma4(a03,y0,w3);
    a10=fma4(a10,y1,w0); a11=fma4(a11,y1,w1); a12=fma4(a12,y1,w2); a13=fma4(a13,y1,w3);
    a20=fma4(a20,y2,w0); a21=fma4(a21,y2,w1); a22=fma4(a22,y2,w2); a23=fma4(a23,y2,w3);
    a30=fma4(a30,y3,w0); a31=fma4(a31,y3,w1); a32=fma4(a32,y3,w2); a33=fma4(a33,y3,w3);
  }
  a00=red8(a00); a01=red8(a01); a02=red8(a02); a03=red8(a03);
  a10=red8(a10); a11=red8(a11); a12=red8(a12); a13=red8(a13);
  a20=red8(a20); a21=red8(a21); a22=red8(a22); a23=red8(a23);
  a30=red8(a30); a31=red8(a31); a32=red8(a32); a33=red8(a33);
  if (kc == 0) {
    const int hb = F4_HL + pOld * 256;
    float4 h0 = smf4[hb + cq],       h1 = smf4[hb + 64 + cq];
    float4 h2 = smf4[hb + 128 + cq], h3 = smf4[hb + 192 + cq];
    float4 n0 = add4(h0, tfast4(add4(make_float4(a00,a01,a02,a03), bcR)));
    float4 n1 = add4(h1, tfast4(add4(make_float4(a10,a11,a12,a13), bcR)));
    float4 n2 = add4(h2, tfast4(add4(make_float4(a20,a21,a22,a23), bcR)));
    float4 n3 = add4(h3, tfast4(add4(make_float4(a30,a31,a32,a33), bcR)));
    smf4[F4_YCP + cq] = n0; smf4[F4_YCP + 64 + cq] = n1;
    smf4[F4_YCQ + cq] = n2; smf4[F4_YCQ + 64 + cq] = n3;
  }
}

__global__ __attribute__((amdgpu_flat_work_group_size(NT, NT)))
void odernn_main(const float* __restrict__ dt,
                 const float* __restrict__ x,
                 const float* __restrict__ bih,
                 const float* __restrict__ bhh,
                 const float* __restrict__ ow1,
                 const float* __restrict__ ob1g,
                 const float* __restrict__ ow2,
                 const float* __restrict__ ob2g,
                 const float* __restrict__ l1bg,
                 const float* __restrict__ muwg,
                 const float* __restrict__ mubg,
                 const float* __restrict__ sb1g,
                 const float* __restrict__ sw2g,
                 const float* __restrict__ sb2g,
                 const float* __restrict__ ws,
                 float* __restrict__ out) {
  __shared__ __align__(16) float sm[SM_TOTF];
  float4* smf4 = (float4*)sm;
  const int tid = threadIdx.x;
  const int b0 = blockIdx.x * 4;

  const float4* wc4  = (const float4*)ws + WF_WCAT;
  const float4* l1s4 = (const float4*)ws + WF_L1;
  const float4* sgs4 = (const float4*)ws + WF_SG;
  const float4* xg4  = (const float4*)x;

  const int cqR = tid >> 3;
  float4 bcR = make_float4(bih[4 * cqR + 0] + bhh[4 * cqR + 0],
                           bih[4 * cqR + 1] + bhh[4 * cqR + 1],
                           bih[4 * cqR + 2] + bhh[4 * cqR + 2],
                           bih[4 * cqR + 3] + bhh[4 * cqR + 3]);

  // prologue staging
  if (tid < 128) { sm[SM_L1B + tid] = l1bg[tid]; sm[SM_MUW + tid] = muwg[tid]; }
  if (tid < 256) { sm[SM_SB1 + tid] = sb1g[tid]; sm[SM_SW2 + tid] = sw2g[tid]; }
  if (tid < 256) smf4[F4_HL + tid] = make_float4(0.f, 0.f, 0.f, 0.f);  // parity 0
  if (tid < 32) {
    int r = tid >> 3, g = tid & 7;
    smf4[F4_X + tid] = xg4[((size_t)(b0 + r) * 100) * 8 + g];
  } else if (tid < 36) {
    int r = tid - 32;
    const float* dp = dt + ((size_t)(b0 + r) * 100) * 2;
    sm[SM_SCL + r] = (dp[1] - dp[0]) * (1.f / 24.f);
  }
  __syncthreads();

  if (tid < 256) {
    // ============ A side: ODE layer-1 (both pairs, pipelined) + mu head ============
    const int q1 = tid >> 4, kc1 = tid & 15;
    float4 w1r[16];
#pragma unroll
    for (int n = 0; n < 4; ++n) {
      int row = 4 * q1 + n;
#pragma unroll
      for (int j = 0; j < 4; ++j)
        w1r[n * 4 + j] = (row < 50)
            ? *(const float4*)&ow1[row * 256 + 64 * j + 4 * kc1]
            : make_float4(0.f, 0.f, 0.f, 0.f);
    }
    float4 ob1r = make_float4(4 * q1 + 0 < 50 ? ob1g[4 * q1 + 0] : 0.f,
                              4 * q1 + 1 < 50 ? ob1g[4 * q1 + 1] : 0.f,
                              4 * q1 + 2 < 50 ? ob1g[4 * q1 + 2] : 0.f,
                              4 * q1 + 3 < 50 ? ob1g[4 * q1 + 3] : 0.f);
    const int wv = tid >> 6, ln = tid & 63;
    const int rH = tid >> 6, low = tid & 63, cqH = low >> 1, kcH = low & 1;
    const float mubv = mubg[0];

    for (int t = 0; t < 100; ++t) {
      const int pOld = t & 1, pNew = pOld ^ 1;
      rnn_phase4(tid, pOld, wc4, smf4, bcR);
      __syncthreads();                                   // h/yc ready
      for (int ph = 0; ph < 33; ++ph) {
        if (ph < 32) {
          const int ycB = (ph & 1) ? F4_YCQ : F4_YCP;
          const int mdB = (ph & 1) ? F4_MIDQ : F4_MIDP;
          float a0 = 0, a1 = 0, a2 = 0, a3 = 0, a4 = 0, a5 = 0, a6 = 0, a7 = 0;
#pragma unroll
          for (int j = 0; j < 4; ++j) {
            float4 y0 = smf4[ycB + 16 * j + kc1];
            float4 y1 = smf4[ycB + 64 + 16 * j + kc1];
            a0 = fma4(a0, y0, w1r[0 * 4 + j]); a1 = fma4(a1, y0, w1r[1 * 4 + j]);
            a2 = fma4(a2, y0, w1r[2 * 4 + j]); a3 = fma4(a3, y0, w1r[3 * 4 + j]);
            a4 = fma4(a4, y1, w1r[0 * 4 + j]); a5 = fma4(a5, y1, w1r[1 * 4 + j]);
            a6 = fma4(a6, y1, w1r[2 * 4 + j]); a7 = fma4(a7, y1, w1r[3 * 4 + j]);
          }
          a0 = red16(a0); a1 = red16(a1); a2 = red16(a2); a3 = red16(a3);
          a4 = red16(a4); a5 = red16(a5); a6 = red16(a6); a7 = red16(a7);
          if (kc1 == 0) {
            smf4[mdB + q1]      = tfast4(add4(make_float4(a0, a1, a2, a3), ob1r));
            smf4[mdB + 16 + q1] = tfast4(add4(make_float4(a4, a5, a6, a7), ob1r));
          }
        }
        __syncthreads();
      }
      // mu-l1 partials: rH(4) x cqH(32) x kcH(2)
      {
        float c0 = 0, c1 = 0, c2 = 0, c3 = 0;
        const float4* hrow = smf4 + F4_HL + pNew * 256 + rH * 64 + kcH * 32;
#pragma unroll 2
        for (int jj = 0; jj < 32; ++jj) {
          float4 h = hrow[jj];
          c0 = fma4(c0, h, l1s4[(0 * 32 + jj) * 64 + low]);
          c1 = fma4(c1, h, l1s4[(1 * 32 + jj) * 64 + low]);
          c2 = fma4(c2, h, l1s4[(2 * 32 + jj) * 64 + low]);
          c3 = fma4(c3, h, l1s4[(3 * 32 + jj) * 64 + low]);
        }
        c0 = red2(c0); c1 = red2(c1); c2 = red2(c2); c3 = red2(c3);
        if (kcH == 0) {
          float4 b = ((const float4*)(sm + SM_L1B))[cqH];
          float4 v = add4(make_float4(c0, c1, c2, c3), b);
          smf4[F4_L1O + rH * 32 + cqH] =
              make_float4(fmaxf(v.x, 0.f), fmaxf(v.y, 0.f),
                          fmaxf(v.z, 0.f), fmaxf(v.w, 0.f));
        }
      }
      __syncthreads();                                   // heads ready
      // mu dots: wave wv -> row wv
      {
        float pm = 0.f;
        if (ln < 32) {
          float4 l = smf4[F4_L1O + wv * 32 + ln];
          float4 w = ((const float4*)(sm + SM_MUW))[ln];
          pm = l.x * w.x + l.y * w.y + l.z * w.z + l.w * w.w;
        }
#pragma unroll
        for (int off = 32; off > 0; off >>= 1) pm += __shfl_down(pm, off);
        if (ln == 0) out[(size_t)(b0 + wv) * 100 + t] = pm + mubv;
      }
    }
  } else {
    // ============ B side: ODE layer-2 + RK4 (both pairs) + sigma head ============
    const int tid2 = tid - 256;
    const int cqB = tid2 >> 2, kc2 = tid2 & 3;
    float4 w2r[16];
#pragma unroll
    for (int c = 0; c < 4; ++c) {
      int col = 4 * cqB + c;
#pragma unroll
      for (int j = 0; j < 4; ++j) {
        float wt[4];
#pragma unroll
        for (int cc = 0; cc < 4; ++cc) {
          int k = 16 * j + 4 * kc2 + cc;
          wt[cc] = (k < 50) ? ow2[col * 50 + k] : 0.f;
        }
        w2r[c * 4 + j] = make_float4(wt[0], wt[1], wt[2], wt[3]);
      }
    }
    float4 ob2r = make_float4(ob2g[4 * cqB + 0], ob2g[4 * cqB + 1],
                              ob2g[4 * cqB + 2], ob2g[4 * cqB + 3]);
    const int wv = tid >> 6, ln = tid & 63;              // wv in 4..7
    const int rH2 = tid2 >> 6, cqS = tid2 & 63;
    const float sb2v = sb2g[0];

    for (int t = 0; t < 100; ++t) {
      const int pOld = t & 1, pNew = pOld ^ 1;
      rnn_phase4(tid, pOld, wc4, smf4, bcR);
      __syncthreads();                                   // h/yc ready
      // ---- ph0: load state regs + stage next x/scl
      float sc0 = sm[SM_SCL + pOld * 4 + 0], sc1 = sm[SM_SCL + pOld * 4 + 1];
      float sc2 = sm[SM_SCL + pOld * 4 + 2], sc3 = sm[SM_SCL + pOld * 4 + 3];
      float4 hP0 = smf4[F4_YCP + cqB], hP1 = smf4[F4_YCP + 64 + cqB];
      float4 hQ0 = smf4[F4_YCQ + cqB], hQ1 = smf4[F4_YCQ + 64 + cqB];
      float4 acP0 = make_float4(0, 0, 0, 0), acP1 = acP0, acQ0 = acP0, acQ1 = acP0;
      if (t < 99) {
        if (tid2 < 32) {
          int r = tid2 >> 3, g = tid2 & 7;
          smf4[F4_X + pNew * 32 + tid2] = xg4[((size_t)(b0 + r) * 100 + t + 1) * 8 + g];
        } else if (tid2 < 36) {
          int r = tid2 - 32;
          const float* dp = dt + ((size_t)(b0 + r) * 100 + t + 1) * 2;
          sm[SM_SCL + pNew * 4 + r] = (dp[1] - dp[0]) * (1.f / 24.f);
        }
      }
      __syncthreads();                                   // ph0 barrier

      auto l2eval = [&](float4& h0, float4& h1, float4& ac0, float4& ac1,
                        float s0, float s1, int mdB, int ycB, int hlB,
                        int s, bool last) {
        float b0 = 0, b1 = 0, b2 = 0, b3 = 0, b4 = 0, b5 = 0, b6 = 0, b7 = 0;
#pragma unroll
        for (int j = 0; j < 4; ++j) {
          float4 m0 = smf4[mdB + 4 * j + kc2];
          float4 m1 = smf4[mdB + 16 + 4 * j + kc2];
          b0 = fma4(b0, m0, w2r[0 * 4 + j]); b1 = fma4(b1, m0, w2r[1 * 4 + j]);
          b2 = fma4(b2, m0, w2r[2 * 4 + j]); b3 = fma4(b3, m0, w2r[3 * 4 + j]);
          b4 = fma4(b4, m1, w2r[0 * 4 + j]); b5 = fma4(b5, m1, w2r[1 * 4 + j]);
          b6 = fma4(b6, m1, w2r[2 * 4 + j]); b7 = fma4(b7, m1, w2r[3 * 4 + j]);
        }
        b0 = red4(b0); b1 = red4(b1); b2 = red4(b2); b3 = red4(b3);
        b4 = red4(b4); b5 = red4(b5); b6 = red4(b6); b7 = red4(b7);
        float4 k0 = muls4(add4(make_float4(b0, b1, b2, b3), ob2r), s0);
        float4 k1 = muls4(add4(make_float4(b4, b5, b6, b7), ob2r), s1);
        float4 y0w, y1w;
        if (s == 0) {
          ac0 = k0; ac1 = k1;
          y0w = axpy4(0.125f, k0, h0); y1w = axpy4(0.125f, k1, h1);
        } else if (s == 1) {
          ac0 = axpy4(2.f, k0, ac0); ac1 = axpy4(2.f, k1, ac1);
          y0w = axpy4(0.125f, k0, h0); y1w = axpy4(0.125f, k1, h1);
        } else if (s == 2) {
          ac0 = axpy4(2.f, k0, ac0); ac1 = axpy4(2.f, k1, ac1);
          y0w = axpy4(0.25f, k0, h0); y1w = axpy4(0.25f, k1, h1);
        } else {
          h0 = axpy4(0.25f / 6.f, add4(ac0, k0), h0);
          h1 = axpy4(0.25f / 6.f, add4(ac1, k1), h1);
          y0w = h0; y1w = h1;
        }
        if (kc2 == 0) {
          smf4[ycB + cqB] = y0w;
          smf4[ycB + 64 + cqB] = y1w;
          if (last) {
            smf4[hlB + cqB] = h0;
            smf4[hlB + 64 + cqB] = h1;
          }
        }
      };

      for (int ph = 1; ph <= 32; ++ph) {
        const int e = (ph - 1) >> 1, s = e & 3;
        if (ph & 1)
          l2eval(hP0, hP1, acP0, acP1, sc0, sc1, F4_MIDP, F4_YCP,
                 F4_HL + pNew * 256, s, e == 15);
        else
          l2eval(hQ0, hQ1, acQ0, acQ1, sc2, sc3, F4_MIDQ, F4_YCQ,
                 F4_HL + pNew * 256 + 128, s, e == 15);
        __syncthreads();
      }
      // sigma-l1: rH2(4) x cqS(64), full K per thread (no reduction)
      {
        float d0 = 0, d1 = 0, d2 = 0, d3 = 0;
        const float4* hrow = smf4 + F4_HL + pNew * 256 + rH2 * 64;
#pragma unroll 2
        for (int kq = 0; kq < 64; ++kq) {
          float4 h = hrow[kq];
          d0 = fma4(d0, h, sgs4[(0 * 64 + kq) * 64 + cqS]);
          d1 = fma4(d1, h, sgs4[(1 * 64 + kq) * 64 + cqS]);
          d2 = fma4(d2, h, sgs4[(2 * 64 + kq) * 64 + cqS]);
          d3 = fma4(d3, h, sgs4[(3 * 64 + kq) * 64 + cqS]);
        }
        float4 sb = ((const float4*)(sm + SM_SB1))[cqS];
        smf4[F4_SG + rH2 * 64 + cqS] = tfast4(add4(make_float4(d0, d1, d2, d3), sb));
      }
      __syncthreads();                                   // heads ready
      // sigma dots: wave wv -> row wv-4
      {
        const int r = wv - 4;
        float4 sv = smf4[F4_SG + r * 64 + ln];
        float4 w = ((const float4*)(sm + SM_SW2))[ln];
        float ps = sv.x * w.x + sv.y * w.y + sv.z * w.z + sv.w * w.w;
#pragma unroll
        for (int off = 32; off > 0; off >>= 1) ps += __shfl_down(ps, off);
        if (ln == 0) {
          float z = ps + sb2v;
          float sp = fmaxf(z, 0.f) + log1pf(expf(-fabsf(z)));
          out[(size_t)102400 + (size_t)(b0 + r) * 100 + t] = sp;
        }
      }
    }
  }
}

extern "C" void kernel_launch(void* const* d_in, const int* in_sizes, int n_in,
                              void* d_out, int out_size, void* d_ws, size_t ws_size,
                              hipStream_t stream) {
  const float* dt  = (const float*)d_in[0];
  const float* x   = (const float*)d_in[1];
  const float* Wih = (const float*)d_in[2];
  const float* bih = (const float*)d_in[3];
  const float* Whh = (const float*)d_in[4];
  const float* bhh = (const float*)d_in[5];
  const float* ow1 = (const float*)d_in[6];
  const float* ob1 = (const float*)d_in[7];
  const float* ow2 = (const float*)d_in[8];
  const float* ob2 = (const float*)d_in[9];
  const float* l1w = (const float*)d_in[10];
  const float* l1b = (const float*)d_in[11];
  const float* muw = (const float*)d_in[12];
  const float* mub = (const float*)d_in[13];
  const float* sw1 = (const float*)d_in[14];
  const float* sb1 = (const float*)d_in[15];
  const float* sw2 = (const float*)d_in[16];
  const float* sb2 = (const float*)d_in[17];
  float* ws  = (float*)d_ws;
  float* out = (float*)d_out;

  prep_w<<<672, 256, 0, stream>>>(Wih, Whh, l1w, sw1, ws);
  odernn_main<<<256, NT, 0, stream>>>(dt, x, bih, bhh, ow1, ob1, ow2, ob2,
                                      l1b, muw, mub, sb1, sw2, sb2, ws, out);
}

// Round 10
// 4327.385 us; speedup vs baseline: 1.0100x; 1.0100x over previous
//
#include <hip/hip_runtime.h>
#include <math.h>

// ODE-RNN forward: B=1024, T=100, D=32, H=256, MID=50 (padded 64), RK4x4.
// Round 10: R9 schedule (A/B wave-specialized, P/Q pipelined, 35 barriers)
// with ROW-SPLIT FAT THREADS: A-thread = 8 neurons x 16k x 1 row (4 LDS
// reads, was 8), B-thread = 8 cols x 16mid x 1 row (4 reads, was 8).
// Weights 128 VGPR/side (256-cap, no waves_per_eu). red16/red4 verified R8.

#define NT 512

// ---- ws layout (float4 units) ----
#define WF_WCAT 0        // [(c*9+gg)][512 tid] f4 : RNN concat weights
#define WF_L1   18432    // [(c*32+jj)][64 low] f4 : mu-l1
#define WF_SG   26624    // [(c*64+kq)][64 cqB] f4 : sigma-l1

// ---- LDS layout (f4 offsets) ----
#define F4_YCP  0        // [2 rows][64]
#define F4_YCQ  128
#define F4_MIDP 256      // [2 rows][16]
#define F4_MIDQ 288
#define F4_HL   320      // [2 parity][4 rows][64]
#define F4_X    832      // [2 parity][4 rows][8]
#define F4_L1O  896      // [4 rows][32]
#define F4_SG   1024     // [4 rows][64]
#define SM_L1B  5120     // float offsets from here
#define SM_SB1  5248
#define SM_MUW  5504
#define SM_SW2  5632
#define SM_SCL  5888     // [2 parity][4 rows]
#define SM_TOTF 5896

__device__ __forceinline__ float fma4(float acc, float4 y, float4 w) {
  acc = fmaf(y.x, w.x, acc); acc = fmaf(y.y, w.y, acc);
  acc = fmaf(y.z, w.z, acc); acc = fmaf(y.w, w.w, acc);
  return acc;
}
__device__ __forceinline__ float4 add4(float4 a, float4 b) {
  return make_float4(a.x + b.x, a.y + b.y, a.z + b.z, a.w + b.w);
}
__device__ __forceinline__ float4 axpy4(float a, float4 xv, float4 yv) {
  return make_float4(fmaf(a, xv.x, yv.x), fmaf(a, xv.y, yv.y),
                     fmaf(a, xv.z, yv.z), fmaf(a, xv.w, yv.w));
}
__device__ __forceinline__ float4 muls4(float4 v, float s) {
  return make_float4(v.x * s, v.y * s, v.z * s, v.w * s);
}
__device__ __forceinline__ float tfast(float x) {
  float ax = fabsf(x);
  float e  = __expf(-2.f * ax);
  float t  = (1.f - e) * __builtin_amdgcn_rcpf(1.f + e);
  return copysignf(t, x);
}
__device__ __forceinline__ float4 tfast4(float4 v) {
  return make_float4(tfast(v.x), tfast(v.y), tfast(v.z), tfast(v.w));
}
// DPP butterfly adds (verified R8): after redN every lane of each aligned
// N-lane group holds the group sum. Pure VALU.
template <int CTRL>
__device__ __forceinline__ float dpp_add(float v) {
  int s = __builtin_amdgcn_update_dpp(0, __float_as_int(v), CTRL, 0xF, 0xF, true);
  return v + __int_as_float(s);
}
__device__ __forceinline__ float red4(float v)  { return dpp_add<0x4E>(dpp_add<0xB1>(v)); }
__device__ __forceinline__ float red8(float v)  {
  return dpp_add<0xB1>(dpp_add<0x4E>(dpp_add<0x141>(v)));
}
__device__ __forceinline__ float red16(float v) {
  return dpp_add<0xB1>(dpp_add<0x4E>(dpp_add<0x141>(dpp_add<0x140>(v))));
}

__global__ void prep_w(const float* __restrict__ Wih, const float* __restrict__ Whh,
                       const float* __restrict__ l1w, const float* __restrict__ sw1,
                       float* __restrict__ ws) {
  int i = blockIdx.x * 256 + threadIdx.x;
  if (i < 73728) {                       // wcat
    int fi = i >> 2, comp = i & 3;
    int j = fi >> 9, tw = fi & 511;
    int c = j / 9, gg = j - c * 9;
    int cq = tw >> 3, kc = tw & 7;
    int k = 36 * kc + 4 * gg + comp, col = 4 * cq + c;
    ws[i] = (k < 32) ? Wih[col * 32 + k] : Whh[col * 256 + (k - 32)];
  } else if (i < 106496) {               // l1: (c*32+jj)*64 + low
    int t = i - 73728;
    int fi = t >> 2, comp = t & 3;
    int low = fi & 63, rest = fi >> 6;
    int c = rest >> 5, jj = rest & 31;
    int cqH = low >> 1, kcH = low & 1;
    int col = 4 * cqH + c, k = 4 * (32 * kcH + jj) + comp;
    ws[73728 + t] = l1w[col * 256 + k];
  } else {                               // sig: (c*64+kq)*64 + cqB
    int t = i - 106496;
    int fi = t >> 2, comp = t & 3;
    int cqB = fi & 63, rest = fi >> 6;
    int c = rest >> 6, kq = rest & 63;
    int col = 4 * cqB + c, k = 4 * kq + comp;
    ws[106496 + t] = sw1[col * 256 + k];
  }
}

// RNN for 4 rows, all 512 threads: (cq 64, kc 8), 4 cols x 4 rows.
__device__ __forceinline__ void rnn_phase4(int tid, int pOld,
                                           const float4* __restrict__ wc4,
                                           float4* smf4, float4 bcR) {
  const int cq = tid >> 3, kc = tid & 7;
  float a00=0,a01=0,a02=0,a03=0, a10=0,a11=0,a12=0,a13=0;
  float a20=0,a21=0,a22=0,a23=0, a30=0,a31=0,a32=0,a33=0;
#pragma unroll 3
  for (int gg = 0; gg < 9; ++gg) {
    int g = kc * 9 + gg;
    float4 w0 = wc4[(0 * 9 + gg) * 512 + tid];
    float4 w1 = wc4[(1 * 9 + gg) * 512 + tid];
    float4 w2 = wc4[(2 * 9 + gg) * 512 + tid];
    float4 w3 = wc4[(3 * 9 + gg) * 512 + tid];
    float4 y0, y1, y2, y3;
    if (g < 8) {
      const int xb = F4_X + pOld * 32;
      y0 = smf4[xb + g]; y1 = smf4[xb + 8 + g];
      y2 = smf4[xb + 16 + g]; y3 = smf4[xb + 24 + g];
    } else {
      const int hb = F4_HL + pOld * 256 + (g - 8);
      y0 = smf4[hb]; y1 = smf4[hb + 64];
      y2 = smf4[hb + 128]; y3 = smf4[hb + 192];
    }
    a00=fma4(a00,y0,w0); a01=fma4(a01,y0,w1); a02=fma4(a02,y0,w2); a03=fma4(a03,y0,w3);
    a10=fma4(a10,y1,w0); a11=fma4(a11,y1,w1); a12=fma4(a12,y1,w2); a13=fma4(a13,y1,w3);
    a20=fma4(a20,y2,w0); a21=fma4(a21,y2,w1); a22=fma4(a22,y2,w2); a23=fma4(a23,y2,w3);
    a30=fma4(a30,y3,w0); a31=fma4(a31,y3,w1); a32=fma4(a32,y3,w2); a33=fma4(a33,y3,w3);
  }
  a00=red8(a00); a01=red8(a01); a02=red8(a02); a03=red8(a03);
  a10=red8(a10); a11=red8(a11); a12=red8(a12); a13=red8(a13);
  a20=red8(a20); a21=red8(a21); a22=red8(a22); a23=red8(a23);
  a30=red8(a30); a31=red8(a31); a32=red8(a32); a33=red8(a33);
  if (kc == 0) {
    const int hb = F4_HL + pOld * 256;
    float4 h0 = smf4[hb + cq],       h1 = smf4[hb + 64 + cq];
    float4 h2 = smf4[hb + 128 + cq], h3 = smf4[hb + 192 + cq];
    float4 n0 = add4(h0, tfast4(add4(make_float4(a00,a01,a02,a03), bcR)));
    float4 n1 = add4(h1, tfast4(add4(make_float4(a10,a11,a12,a13), bcR)));
    float4 n2 = add4(h2, tfast4(add4(make_float4(a20,a21,a22,a23), bcR)));
    float4 n3 = add4(h3, tfast4(add4(make_float4(a30,a31,a32,a33), bcR)));
    smf4[F4_YCP + cq] = n0; smf4[F4_YCP + 64 + cq] = n1;
    smf4[F4_YCQ + cq] = n2; smf4[F4_YCQ + 64 + cq] = n3;
  }
}

__global__ __attribute__((amdgpu_flat_work_group_size(NT, NT)))
void odernn_main(const float* __restrict__ dt,
                 const float* __restrict__ x,
                 const float* __restrict__ bih,
                 const float* __restrict__ bhh,
                 const float* __restrict__ ow1,
                 const float* __restrict__ ob1g,
                 const float* __restrict__ ow2,
                 const float* __restrict__ ob2g,
                 const float* __restrict__ l1bg,
                 const float* __restrict__ muwg,
                 const float* __restrict__ mubg,
                 const float* __restrict__ sb1g,
                 const float* __restrict__ sw2g,
                 const float* __restrict__ sb2g,
                 const float* __restrict__ ws,
                 float* __restrict__ out) {
  __shared__ __align__(16) float sm[SM_TOTF];
  float4* smf4 = (float4*)sm;
  const int tid = threadIdx.x;
  const int b0 = blockIdx.x * 4;

  const float4* wc4  = (const float4*)ws + WF_WCAT;
  const float4* l1s4 = (const float4*)ws + WF_L1;
  const float4* sgs4 = (const float4*)ws + WF_SG;
  const float4* xg4  = (const float4*)x;

  const int cqR = tid >> 3;
  float4 bcR = make_float4(bih[4 * cqR + 0] + bhh[4 * cqR + 0],
                           bih[4 * cqR + 1] + bhh[4 * cqR + 1],
                           bih[4 * cqR + 2] + bhh[4 * cqR + 2],
                           bih[4 * cqR + 3] + bhh[4 * cqR + 3]);

  // prologue staging
  if (tid < 128) { sm[SM_L1B + tid] = l1bg[tid]; sm[SM_MUW + tid] = muwg[tid]; }
  if (tid < 256) { sm[SM_SB1 + tid] = sb1g[tid]; sm[SM_SW2 + tid] = sw2g[tid]; }
  if (tid < 256) smf4[F4_HL + tid] = make_float4(0.f, 0.f, 0.f, 0.f);  // parity 0
  if (tid < 32) {
    int r = tid >> 3, g = tid & 7;
    smf4[F4_X + tid] = xg4[((size_t)(b0 + r) * 100) * 8 + g];
  } else if (tid < 36) {
    int r = tid - 32;
    const float* dp = dt + ((size_t)(b0 + r) * 100) * 2;
    sm[SM_SCL + r] = (dp[1] - dp[0]) * (1.f / 24.f);
  }
  __syncthreads();

  if (tid < 256) {
    // ===== A side: L1 (row-split fat: 8 neurons x 16k x 1 row) + mu head =====
    const int q1 = tid >> 5, rA = (tid >> 4) & 1, kc1 = tid & 15;
    float4 w1r[8][4];          // 128 VGPR
#pragma unroll
    for (int n = 0; n < 8; ++n) {
      int row = 8 * q1 + n;
#pragma unroll
      for (int j = 0; j < 4; ++j)
        w1r[n][j] = (row < 50)
            ? *(const float4*)&ow1[row * 256 + 4 * (kc1 + 16 * j)]
            : make_float4(0.f, 0.f, 0.f, 0.f);
    }
    float ob1t[8];
#pragma unroll
    for (int n = 0; n < 8; ++n)
      ob1t[n] = (8 * q1 + n < 50) ? ob1g[8 * q1 + n] : 0.f;
    float4 ob1lo = make_float4(ob1t[0], ob1t[1], ob1t[2], ob1t[3]);
    float4 ob1hi = make_float4(ob1t[4], ob1t[5], ob1t[6], ob1t[7]);

    const int wv = tid >> 6, ln = tid & 63;
    const int rH = tid >> 6, low = tid & 63, cqH = low >> 1, kcH = low & 1;
    const float mubv = mubg[0];

    for (int t = 0; t < 100; ++t) {
      const int pOld = t & 1, pNew = pOld ^ 1;
      rnn_phase4(tid, pOld, wc4, smf4, bcR);
      __syncthreads();                                   // h/yc ready
      for (int ph = 0; ph < 33; ++ph) {
        if (ph < 32) {
          const int ycB = ((ph & 1) ? F4_YCQ : F4_YCP) + rA * 64;
          const int mdB = ((ph & 1) ? F4_MIDQ : F4_MIDP) + rA * 16;
          float4 y0 = smf4[ycB + kc1];
          float4 y1 = smf4[ycB + 16 + kc1];
          float4 y2 = smf4[ycB + 32 + kc1];
          float4 y3 = smf4[ycB + 48 + kc1];
          float a0 = 0, a1 = 0, a2 = 0, a3 = 0, a4 = 0, a5 = 0, a6 = 0, a7 = 0;
          a0 = fma4(a0, y0, w1r[0][0]); a0 = fma4(a0, y1, w1r[0][1]);
          a0 = fma4(a0, y2, w1r[0][2]); a0 = fma4(a0, y3, w1r[0][3]);
          a1 = fma4(a1, y0, w1r[1][0]); a1 = fma4(a1, y1, w1r[1][1]);
          a1 = fma4(a1, y2, w1r[1][2]); a1 = fma4(a1, y3, w1r[1][3]);
          a2 = fma4(a2, y0, w1r[2][0]); a2 = fma4(a2, y1, w1r[2][1]);
          a2 = fma4(a2, y2, w1r[2][2]); a2 = fma4(a2, y3, w1r[2][3]);
          a3 = fma4(a3, y0, w1r[3][0]); a3 = fma4(a3, y1, w1r[3][1]);
          a3 = fma4(a3, y2, w1r[3][2]); a3 = fma4(a3, y3, w1r[3][3]);
          a4 = fma4(a4, y0, w1r[4][0]); a4 = fma4(a4, y1, w1r[4][1]);
          a4 = fma4(a4, y2, w1r[4][2]); a4 = fma4(a4, y3, w1r[4][3]);
          a5 = fma4(a5, y0, w1r[5][0]); a5 = fma4(a5, y1, w1r[5][1]);
          a5 = fma4(a5, y2, w1r[5][2]); a5 = fma4(a5, y3, w1r[5][3]);
          a6 = fma4(a6, y0, w1r[6][0]); a6 = fma4(a6, y1, w1r[6][1]);
          a6 = fma4(a6, y2, w1r[6][2]); a6 = fma4(a6, y3, w1r[6][3]);
          a7 = fma4(a7, y0, w1r[7][0]); a7 = fma4(a7, y1, w1r[7][1]);
          a7 = fma4(a7, y2, w1r[7][2]); a7 = fma4(a7, y3, w1r[7][3]);
          a0 = red16(a0); a1 = red16(a1); a2 = red16(a2); a3 = red16(a3);
          a4 = red16(a4); a5 = red16(a5); a6 = red16(a6); a7 = red16(a7);
          if (kc1 == 0) {
            smf4[mdB + q1 * 2]     = tfast4(add4(make_float4(a0, a1, a2, a3), ob1lo));
            smf4[mdB + q1 * 2 + 1] = tfast4(add4(make_float4(a4, a5, a6, a7), ob1hi));
          }
        }
        __syncthreads();
      }
      // mu-l1 partials: rH(4) x cqH(32) x kcH(2)
      {
        float c0 = 0, c1 = 0, c2 = 0, c3 = 0;
        const float4* hrow = smf4 + F4_HL + pNew * 256 + rH * 64 + kcH * 32;
#pragma unroll 2
        for (int jj = 0; jj < 32; ++jj) {
          float4 h = hrow[jj];
          c0 = fma4(c0, h, l1s4[(0 * 32 + jj) * 64 + low]);
          c1 = fma4(c1, h, l1s4[(1 * 32 + jj) * 64 + low]);
          c2 = fma4(c2, h, l1s4[(2 * 32 + jj) * 64 + low]);
          c3 = fma4(c3, h, l1s4[(3 * 32 + jj) * 64 + low]);
        }
        c0 = dpp_add<0xB1>(c0); c1 = dpp_add<0xB1>(c1);
        c2 = dpp_add<0xB1>(c2); c3 = dpp_add<0xB1>(c3);
        if (kcH == 0) {
          float4 b = ((const float4*)(sm + SM_L1B))[cqH];
          float4 v = add4(make_float4(c0, c1, c2, c3), b);
          smf4[F4_L1O + rH * 32 + cqH] =
              make_float4(fmaxf(v.x, 0.f), fmaxf(v.y, 0.f),
                          fmaxf(v.z, 0.f), fmaxf(v.w, 0.f));
        }
      }
      __syncthreads();                                   // heads ready
      // mu dots: wave wv -> row wv
      {
        float pm = 0.f;
        if (ln < 32) {
          float4 l = smf4[F4_L1O + wv * 32 + ln];
          float4 w = ((const float4*)(sm + SM_MUW))[ln];
          pm = l.x * w.x + l.y * w.y + l.z * w.z + l.w * w.w;
        }
#pragma unroll
        for (int off = 32; off > 0; off >>= 1) pm += __shfl_down(pm, off);
        if (ln == 0) out[(size_t)(b0 + wv) * 100 + t] = pm + mubv;
      }
    }
  } else {
    // ===== B side: L2+RK4 (row-split fat: 8 cols x 16mid x 1 row) + sigma =====
    const int tid2 = tid - 256;
    const int cq = tid2 >> 3, rB = (tid2 >> 2) & 1, kc2 = tid2 & 3;
    float4 w2r[8][4];          // 128 VGPR
#pragma unroll
    for (int c = 0; c < 8; ++c) {
      int col = 8 * cq + c;
#pragma unroll
      for (int j = 0; j < 4; ++j) {
        float wt[4];
#pragma unroll
        for (int cc = 0; cc < 4; ++cc) {
          int m = 4 * (kc2 + 4 * j) + cc;
          wt[cc] = (m < 50) ? ow2[col * 50 + m] : 0.f;
        }
        w2r[c][j] = make_float4(wt[0], wt[1], wt[2], wt[3]);
      }
    }
    float4 ob2lo = make_float4(ob2g[8 * cq + 0], ob2g[8 * cq + 1],
                               ob2g[8 * cq + 2], ob2g[8 * cq + 3]);
    float4 ob2hi = make_float4(ob2g[8 * cq + 4], ob2g[8 * cq + 5],
                               ob2g[8 * cq + 6], ob2g[8 * cq + 7]);
    const int wv = tid >> 6, ln = tid & 63;              // wv in 4..7
    const int rH2 = tid2 >> 6, cqS = tid2 & 63;
    const float sb2v = sb2g[0];

    for (int t = 0; t < 100; ++t) {
      const int pOld = t & 1, pNew = pOld ^ 1;
      rnn_phase4(tid, pOld, wc4, smf4, bcR);
      __syncthreads();                                   // h/yc ready
      // ---- ph0: load state regs + stage next x/scl
      float scP = sm[SM_SCL + pOld * 4 + rB];
      float scQ = sm[SM_SCL + pOld * 4 + 2 + rB];
      float4 hP0 = smf4[F4_YCP + rB * 64 + cq * 2], hP1 = smf4[F4_YCP + rB * 64 + cq * 2 + 1];
      float4 hQ0 = smf4[F4_YCQ + rB * 64 + cq * 2], hQ1 = smf4[F4_YCQ + rB * 64 + cq * 2 + 1];
      float4 acP0 = make_float4(0, 0, 0, 0), acP1 = acP0, acQ0 = acP0, acQ1 = acP0;
      if (t < 99) {
        if (tid2 < 32) {
          int r = tid2 >> 3, g = tid2 & 7;
          smf4[F4_X + pNew * 32 + tid2] = xg4[((size_t)(b0 + r) * 100 + t + 1) * 8 + g];
        } else if (tid2 < 36) {
          int r = tid2 - 32;
          const float* dp = dt + ((size_t)(b0 + r) * 100 + t + 1) * 2;
          sm[SM_SCL + pNew * 4 + r] = (dp[1] - dp[0]) * (1.f / 24.f);
        }
      }
      __syncthreads();                                   // ph0 barrier

      auto l2eval = [&](float4& h0, float4& h1, float4& ac0, float4& ac1,
                        float sc, int mdB, int ycB, int hlB, int s, bool last) {
        float4 m0 = smf4[mdB + kc2];
        float4 m1 = smf4[mdB + 4 + kc2];
        float4 m2 = smf4[mdB + 8 + kc2];
        float4 m3 = smf4[mdB + 12 + kc2];
        float b0 = 0, b1 = 0, b2 = 0, b3 = 0, b4 = 0, b5 = 0, b6 = 0, b7 = 0;
        b0 = fma4(b0, m0, w2r[0][0]); b0 = fma4(b0, m1, w2r[0][1]);
        b0 = fma4(b0, m2, w2r[0][2]); b0 = fma4(b0, m3, w2r[0][3]);
        b1 = fma4(b1, m0, w2r[1][0]); b1 = fma4(b1, m1, w2r[1][1]);
        b1 = fma4(b1, m2, w2r[1][2]); b1 = fma4(b1, m3, w2r[1][3]);
        b2 = fma4(b2, m0, w2r[2][0]); b2 = fma4(b2, m1, w2r[2][1]);
        b2 = fma4(b2, m2, w2r[2][2]); b2 = fma4(b2, m3, w2r[2][3]);
        b3 = fma4(b3, m0, w2r[3][0]); b3 = fma4(b3, m1, w2r[3][1]);
        b3 = fma4(b3, m2, w2r[3][2]); b3 = fma4(b3, m3, w2r[3][3]);
        b4 = fma4(b4, m0, w2r[4][0]); b4 = fma4(b4, m1, w2r[4][1]);
        b4 = fma4(b4, m2, w2r[4][2]); b4 = fma4(b4, m3, w2r[4][3]);
        b5 = fma4(b5, m0, w2r[5][0]); b5 = fma4(b5, m1, w2r[5][1]);
        b5 = fma4(b5, m2, w2r[5][2]); b5 = fma4(b5, m3, w2r[5][3]);
        b6 = fma4(b6, m0, w2r[6][0]); b6 = fma4(b6, m1, w2r[6][1]);
        b6 = fma4(b6, m2, w2r[6][2]); b6 = fma4(b6, m3, w2r[6][3]);
        b7 = fma4(b7, m0, w2r[7][0]); b7 = fma4(b7, m1, w2r[7][1]);
        b7 = fma4(b7, m2, w2r[7][2]); b7 = fma4(b7, m3, w2r[7][3]);
        b0 = red4(b0); b1 = red4(b1); b2 = red4(b2); b3 = red4(b3);
        b4 = red4(b4); b5 = red4(b5); b6 = red4(b6); b7 = red4(b7);
        float4 k0 = muls4(add4(make_float4(b0, b1, b2, b3), ob2lo), sc);
        float4 k1 = muls4(add4(make_float4(b4, b5, b6, b7), ob2hi), sc);
        float4 y0w, y1w;
        if (s == 0) {
          ac0 = k0; ac1 = k1;
          y0w = axpy4(0.125f, k0, h0); y1w = axpy4(0.125f, k1, h1);
        } else if (s == 1) {
          ac0 = axpy4(2.f, k0, ac0); ac1 = axpy4(2.f, k1, ac1);
          y0w = axpy4(0.125f, k0, h0); y1w = axpy4(0.125f, k1, h1);
        } else if (s == 2) {
          ac0 = axpy4(2.f, k0, ac0); ac1 = axpy4(2.f, k1, ac1);
          y0w = axpy4(0.25f, k0, h0); y1w = axpy4(0.25f, k1, h1);
        } else {
          h0 = axpy4(0.25f / 6.f, add4(ac0, k0), h0);
          h1 = axpy4(0.25f / 6.f, add4(ac1, k1), h1);
          y0w = h0; y1w = h1;
        }
        if (kc2 == 0) {
          smf4[ycB + cq * 2] = y0w;
          smf4[ycB + cq * 2 + 1] = y1w;
          if (last) {
            smf4[hlB + cq * 2] = h0;
            smf4[hlB + cq * 2 + 1] = h1;
          }
        }
      };

      for (int ph = 1; ph <= 32; ++ph) {
        const int e = (ph - 1) >> 1, s = e & 3;
        if (ph & 1)
          l2eval(hP0, hP1, acP0, acP1, scP, F4_MIDP + rB * 16, F4_YCP + rB * 64,
                 F4_HL + pNew * 256 + rB * 64, s, e == 15);
        else
          l2eval(hQ0, hQ1, acQ0, acQ1, scQ, F4_MIDQ + rB * 16, F4_YCQ + rB * 64,
                 F4_HL + pNew * 256 + 128 + rB * 64, s, e == 15);
        __syncthreads();
      }
      // sigma-l1: rH2(4) x cqS(64), full K per thread
      {
        float d0 = 0, d1 = 0, d2 = 0, d3 = 0;
        const float4* hrow = smf4 + F4_HL + pNew * 256 + rH2 * 64;
#pragma unroll 2
        for (int kq = 0; kq < 64; ++kq) {
          float4 h = hrow[kq];
          d0 = fma4(d0, h, sgs4[(0 * 64 + kq) * 64 + cqS]);
          d1 = fma4(d1, h, sgs4[(1 * 64 + kq) * 64 + cqS]);
          d2 = fma4(d2, h, sgs4[(2 * 64 + kq) * 64 + cqS]);
          d3 = fma4(d3, h, sgs4[(3 * 64 + kq) * 64 + cqS]);
        }
        float4 sb = ((const float4*)(sm + SM_SB1))[cqS];
        smf4[F4_SG + rH2 * 64 + cqS] = tfast4(add4(make_float4(d0, d1, d2, d3), sb));
      }
      __syncthreads();                                   // heads ready
      // sigma dots: wave wv -> row wv-4
      {
        const int r = wv - 4;
        float4 sv = smf4[F4_SG + r * 64 + ln];
        float4 w = ((const float4*)(sm + SM_SW2))[ln];
        float ps = sv.x * w.x + sv.y * w.y + sv.z * w.z + sv.w * w.w;
#pragma unroll
        for (int off = 32; off > 0; off >>= 1) ps += __shfl_down(ps, off);
        if (ln == 0) {
          float z = ps + sb2v;
          float sp = fmaxf(z, 0.f) + log1pf(expf(-fabsf(z)));
          out[(size_t)102400 + (size_t)(b0 + r) * 100 + t] = sp;
        }
      }
    }
  }
}

extern "C" void kernel_launch(void* const* d_in, const int* in_sizes, int n_in,
                              void* d_out, int out_size, void* d_ws, size_t ws_size,
                              hipStream_t stream) {
  const float* dt  = (const float*)d_in[0];
  const float* x   = (const float*)d_in[1];
  const float* Wih = (const float*)d_in[2];
  const float* bih = (const float*)d_in[3];
  const float* Whh = (const float*)d_in[4];
  const float* bhh = (const float*)d_in[5];
  const float* ow1 = (const float*)d_in[6];
  const float* ob1 = (const float*)d_in[7];
  const float* ow2 = (const float*)d_in[8];
  const float* ob2 = (const float*)d_in[9];
  const float* l1w = (const float*)d_in[10];
  const float* l1b = (const float*)d_in[11];
  const float* muw = (const float*)d_in[12];
  const float* mub = (const float*)d_in[13];
  const float* sw1 = (const float*)d_in[14];
  const float* sb1 = (const float*)d_in[15];
  const float* sw2 = (const float*)d_in[16];
  const float* sb2 = (const float*)d_in[17];
  float* ws  = (float*)d_ws;
  float* out = (float*)d_out;

  prep_w<<<672, 256, 0, stream>>>(Wih, Whh, l1w, sw1, ws);
  odernn_main<<<256, NT, 0, stream>>>(dt, x, bih, bhh, ow1, ob1, ow2, ob2,
                                      l1b, muw, mub, sb1, sw2, sb2, ws, out);
}

// Round 11
// 4077.147 us; speedup vs baseline: 1.0720x; 1.0614x over previous
//
#include <hip/hip_runtime.h>
#include <math.h>

// ODE-RNN forward: B=1024, T=100, D=32, H=256, MID=50 (padded 64), RK4x4.
// Round 11: MIXED-PHASE P/Q SCHEDULE. 4 rows = pairs P{0,1}, Q{2,3}; Q runs
// one sub-phase behind P so EVERY phase = FMA-partial(one pair, 512 thr) +
// LDS-reduce/RK4(other pair, 128 thr). Kills the pure-F/pure-L burst
// alternation that kept pipes from overlapping in R4-R10. Weight-reg tiles
// verbatim R4 (64 VGPR); DPP red4 verified R8; dense f4 reduces.

#define NT 512

// ---- ws layout (floats): identical to R4 (proven) ----
#define WS_WCAT 0        // [72 g][256 j][4 c]
#define WS_L1P  73728    // [64 g][128 j][4 c]
#define WS_SW1  106496   // [64 g][256 j][4 c]
#define WS_TOT  172032

// ---- LDS layout (f4 offsets) ----
#define F4_PR1P 0        // 64 slabs x 17  (slab = kc1*2+rx)
#define F4_PR1Q 1088
#define F4_PR2P 2176     // 16 slabs x 65  (slab = kc2*2+rx)
#define F4_PR2Q 3216
#define F4_PRR  2176     // alias: RNN partials, 32 slabs x 65
#define F4_PH1  0        // alias: mu-head partials, 64 slabs x 33
#define F4_PH2  2176     // alias: sig-head partials, 32 slabs x 65
#define F4_YCP  4256     // [2][64]
#define F4_YCQ  4384
#define F4_MIDP 4512     // [2][16]
#define F4_MIDQ 4544
#define F4_HS   4576     // [4][64]
#define F4_XS   4832     // [4][8]
#define F4_L1O  4864     // [4][32]
#define F4_SG   4992     // [4][64]
#define F4_END  5248
#define SM_BC   (F4_END * 4)
#define SM_OB1  (SM_BC + 256)
#define SM_OB2  (SM_OB1 + 64)
#define SM_L1B  (SM_OB2 + 256)
#define SM_SB1  (SM_L1B + 128)
#define SM_MUW  (SM_SB1 + 256)
#define SM_SW2  (SM_MUW + 128)
#define SM_SCL  (SM_SW2 + 256)
#define SM_TOTF (SM_SCL + 8)
#define SMEM_BYTES (SM_TOTF * 4)

__device__ __forceinline__ float fma4(float acc, float4 y, float4 w) {
  acc = fmaf(y.x, w.x, acc); acc = fmaf(y.y, w.y, acc);
  acc = fmaf(y.z, w.z, acc); acc = fmaf(y.w, w.w, acc);
  return acc;
}
__device__ __forceinline__ float4 add4(float4 a, float4 b) {
  return make_float4(a.x + b.x, a.y + b.y, a.z + b.z, a.w + b.w);
}
__device__ __forceinline__ float4 axpy4(float a, float4 xv, float4 yv) {
  return make_float4(fmaf(a, xv.x, yv.x), fmaf(a, xv.y, yv.y),
                     fmaf(a, xv.z, yv.z), fmaf(a, xv.w, yv.w));
}
__device__ __forceinline__ float4 muls4(float4 v, float s) {
  return make_float4(v.x * s, v.y * s, v.z * s, v.w * s);
}
__device__ __forceinline__ float tfast(float x) {
  float ax = fabsf(x);
  float e  = __expf(-2.f * ax);
  float t  = (1.f - e) * __builtin_amdgcn_rcpf(1.f + e);
  return copysignf(t, x);
}
__device__ __forceinline__ float4 tfast4(float4 v) {
  return make_float4(tfast(v.x), tfast(v.y), tfast(v.z), tfast(v.w));
}
// DPP butterfly adds (HW-verified R8): quad_perm xor1/xor2, pure VALU.
template <int CTRL>
__device__ __forceinline__ float dpp_add(float v) {
  int s = __builtin_amdgcn_update_dpp(0, __float_as_int(v), CTRL, 0xF, 0xF, true);
  return v + __int_as_float(s);
}
__device__ __forceinline__ float4 red4f4(float4 v) {
  v.x = dpp_add<0xB1>(v.x); v.y = dpp_add<0xB1>(v.y);
  v.z = dpp_add<0xB1>(v.z); v.w = dpp_add<0xB1>(v.w);
  v.x = dpp_add<0x4E>(v.x); v.y = dpp_add<0x4E>(v.y);
  v.z = dpp_add<0x4E>(v.z); v.w = dpp_add<0x4E>(v.w);
  return v;
}

__global__ void prep_w(const float* __restrict__ Wih, const float* __restrict__ Whh,
                       const float* __restrict__ l1w, const float* __restrict__ sw1,
                       float* __restrict__ ws) {
  int i = blockIdx.x * 256 + threadIdx.x;
  if (i < 73728) {                       // Wcat4
    int g = i >> 10, rem = i & 1023, j = rem >> 2, c = rem & 3;
    int k = 4 * g + c;
    ws[i] = (k < 32) ? Wih[j * 32 + k] : Whh[j * 256 + (k - 32)];
  } else if (i < 106496) {               // l1p4
    int t = i - 73728;
    int g = t >> 9, rem = t & 511, j = rem >> 2, c = rem & 3;
    ws[i] = l1w[j * 256 + 4 * g + c];
  } else if (i < WS_TOT) {               // sw1p4
    int t = i - 106496;
    int g = t >> 10, rem = t & 1023, j = rem >> 2, c = rem & 3;
    ws[i] = sw1[j * 256 + 4 * g + c];
  }
}

__global__ __attribute__((amdgpu_flat_work_group_size(NT, NT)))
void odernn_main(const float* __restrict__ dt,
                 const float* __restrict__ x,
                 const float* __restrict__ bih,
                 const float* __restrict__ bhh,
                 const float* __restrict__ ow1,
                 const float* __restrict__ ob1g,
                 const float* __restrict__ ow2,
                 const float* __restrict__ ob2g,
                 const float* __restrict__ l1bg,
                 const float* __restrict__ muwg,
                 const float* __restrict__ mubg,
                 const float* __restrict__ sb1g,
                 const float* __restrict__ sw2g,
                 const float* __restrict__ sb2g,
                 const float* __restrict__ ws,
                 float* __restrict__ out) {
  extern __shared__ __align__(16) float sm[];
  float4* f4 = (float4*)sm;
  const int tid = threadIdx.x;
  const int b0 = blockIdx.x * 4;

  const float4* wcat4 = (const float4*)(ws + WS_WCAT);
  const float4* l1w4  = (const float4*)(ws + WS_L1P);
  const float4* sw14  = (const float4*)(ws + WS_SW1);
  const float4* xg4   = (const float4*)x;

  // ---- persistent ODE weights: R4 verbatim (64 VGPR, no duplication)
  const int q1 = tid & 15, kc1 = tid >> 4;          // L1: mid-quad q1, k-slice 8
  const int cq2 = tid & 63, kc2 = tid >> 6;         // L2: out-quad cq2, mid-slice 8
  float4 w1r[4][2];
  float4 w2r[4][2];
  {
#pragma unroll
    for (int n = 0; n < 4; ++n) {
      int row = 4 * q1 + n;
#pragma unroll
      for (int g = 0; g < 2; ++g) {
        if (row < 50)
          w1r[n][g] = *(const float4*)&ow1[row * 256 + kc1 * 8 + 4 * g];
        else
          w1r[n][g] = make_float4(0.f, 0.f, 0.f, 0.f);
      }
    }
    float w2tmp[4];
#pragma unroll
    for (int n = 0; n < 4; ++n) {
      int col = 4 * cq2 + n;
#pragma unroll
      for (int g = 0; g < 2; ++g) {
#pragma unroll
        for (int c = 0; c < 4; ++c) {
          int k = kc2 * 8 + 4 * g + c;
          w2tmp[c] = (k < 50) ? ow2[col * 50 + k] : 0.f;
        }
        w2r[n][g] = make_float4(w2tmp[0], w2tmp[1], w2tmp[2], w2tmp[3]);
      }
    }
  }

  // ---- one-time staging
  if (tid < 256) {
    sm[SM_BC + tid]  = bih[tid] + bhh[tid];
    sm[SM_OB2 + tid] = ob2g[tid];
    sm[SM_SB1 + tid] = sb1g[tid];
    sm[SM_SW2 + tid] = sw2g[tid];
  }
  if (tid < 64)  sm[SM_OB1 + tid] = (tid < 50) ? ob1g[tid] : 0.f;
  if (tid < 128) { sm[SM_L1B + tid] = l1bg[tid]; sm[SM_MUW + tid] = muwg[tid]; }
  if (tid < 256) f4[F4_HS + tid] = make_float4(0.f, 0.f, 0.f, 0.f);
  if (tid < 32) {
    int r = tid >> 3, g = tid & 7;
    f4[F4_XS + tid] = xg4[((size_t)(b0 + r) * 100) * 8 + g];
  } else if (tid < 36) {
    int r = tid - 32;
    const float* dp = dt + ((size_t)(b0 + r) * 100) * 2;
    sm[SM_SCL + r] = (dp[1] - dp[0]) * (1.f / 24.f);
  }
  __syncthreads();

  const float mubv = mubg[0], sb2v = sb2g[0];
  const float4* bc4   = (const float4*)(sm + SM_BC);
  const float4* ob1_4 = (const float4*)(sm + SM_OB1);
  const float4* ob2_4 = (const float4*)(sm + SM_OB2);
  const float4* l1b4  = (const float4*)(sm + SM_L1B);
  const float4* sb14  = (const float4*)(sm + SM_SB1);
  const float4* muw4  = (const float4*)(sm + SM_MUW);
  const float4* sw24  = (const float4*)(sm + SM_SW2);

  // state-holder indexing (tid < 128): row-within-pair rxS, out-quad cqS
  const int cqS = tid & 63, rxS = (tid >> 6) & 1;
  float4 hP = make_float4(0, 0, 0, 0), acP = hP, hQ = hP, acQ = hP;
  float scP = 0.f, scQ = 0.f;

  const int wv = tid >> 6, ln = tid & 63;

  // ---- sub-phase lambdas ----
  auto L1PART = [&](int ycB, int prB) {
    float4 p0 = make_float4(0, 0, 0, 0), p1 = p0;
#pragma unroll
    for (int g = 0; g < 2; ++g) {
      float4 y0 = f4[ycB + kc1 * 2 + g];          // row 0 of pair
      float4 y1 = f4[ycB + 64 + kc1 * 2 + g];     // row 1 of pair
      p0.x = fma4(p0.x, y0, w1r[0][g]); p0.y = fma4(p0.y, y0, w1r[1][g]);
      p0.z = fma4(p0.z, y0, w1r[2][g]); p0.w = fma4(p0.w, y0, w1r[3][g]);
      p1.x = fma4(p1.x, y1, w1r[0][g]); p1.y = fma4(p1.y, y1, w1r[1][g]);
      p1.z = fma4(p1.z, y1, w1r[2][g]); p1.w = fma4(p1.w, y1, w1r[3][g]);
    }
    f4[prB + (kc1 * 2 + 0) * 17 + q1] = p0;
    f4[prB + (kc1 * 2 + 1) * 17 + q1] = p1;
  };
  auto L1RED = [&](int prB, int midB) {           // tid < 128
    const int qr = (tid >> 2) & 15, sub = tid & 3, rx = tid >> 6;
    float4 v = make_float4(0, 0, 0, 0);
#pragma unroll
    for (int i = 0; i < 8; ++i)
      v = add4(v, f4[prB + ((sub * 8 + i) * 2 + rx) * 17 + qr]);
    v = red4f4(v);
    if (sub == 0)
      f4[midB + rx * 16 + qr] = tfast4(add4(v, ob1_4[qr]));
  };
  auto L2PART = [&](int midB, int prB) {
    float4 p0 = make_float4(0, 0, 0, 0), p1 = p0;
#pragma unroll
    for (int g = 0; g < 2; ++g) {
      float4 m0 = f4[midB + kc2 * 2 + g];
      float4 m1 = f4[midB + 16 + kc2 * 2 + g];
      p0.x = fma4(p0.x, m0, w2r[0][g]); p0.y = fma4(p0.y, m0, w2r[1][g]);
      p0.z = fma4(p0.z, m0, w2r[2][g]); p0.w = fma4(p0.w, m0, w2r[3][g]);
      p1.x = fma4(p1.x, m1, w2r[0][g]); p1.y = fma4(p1.y, m1, w2r[1][g]);
      p1.z = fma4(p1.z, m1, w2r[2][g]); p1.w = fma4(p1.w, m1, w2r[3][g]);
    }
    f4[prB + (kc2 * 2 + 0) * 65 + cq2] = p0;
    f4[prB + (kc2 * 2 + 1) * 65 + cq2] = p1;
  };
  auto L2RED = [&](float4& h, float4& ac, float sc, int prB, int ycB,
                   int hsRow, int e) {            // tid < 128
    float4 v = ob2_4[cqS];
#pragma unroll
    for (int i = 0; i < 8; ++i)
      v = add4(v, f4[prB + (i * 2 + rxS) * 65 + cqS]);
    float4 kv = muls4(v, sc);
    const int s = e & 3;
    float4 ycw;
    if (s == 0) {
      ac = kv;                      ycw = axpy4(0.125f, kv, h);
    } else if (s == 1) {
      ac = axpy4(2.f, kv, ac);      ycw = axpy4(0.125f, kv, h);
    } else if (s == 2) {
      ac = axpy4(2.f, kv, ac);      ycw = axpy4(0.25f, kv, h);
    } else {
      h = axpy4(0.25f / 6.f, add4(ac, kv), h);
      ycw = h;
    }
    f4[ycB + rxS * 64 + cqS] = ycw;
    if (e == 15) f4[F4_HS + hsRow * 64 + cqS] = h;
  };

  for (int t = 0; t < 100; ++t) {
    // ===== RNN partials (all 512, 4 rows): R4 verbatim FMA, prR store
    {
      const int jq = tid & 63, kc = tid >> 6;
      float4 a0 = make_float4(0, 0, 0, 0), a1 = a0, a2 = a0, a3 = a0;
#pragma unroll 3
      for (int gg = 0; gg < 9; ++gg) {
        int g = kc * 9 + gg;
        float4 w0 = wcat4[g * 256 + 4 * jq + 0];
        float4 w1 = wcat4[g * 256 + 4 * jq + 1];
        float4 w2 = wcat4[g * 256 + 4 * jq + 2];
        float4 w3 = wcat4[g * 256 + 4 * jq + 3];
        float4 y0 = (g < 8) ? f4[F4_XS + g]      : f4[F4_HS + (g - 8)];
        float4 y1 = (g < 8) ? f4[F4_XS + 8 + g]  : f4[F4_HS + 64 + (g - 8)];
        float4 y2 = (g < 8) ? f4[F4_XS + 16 + g] : f4[F4_HS + 128 + (g - 8)];
        float4 y3 = (g < 8) ? f4[F4_XS + 24 + g] : f4[F4_HS + 192 + (g - 8)];
        a0.x = fma4(a0.x, y0, w0); a0.y = fma4(a0.y, y0, w1);
        a0.z = fma4(a0.z, y0, w2); a0.w = fma4(a0.w, y0, w3);
        a1.x = fma4(a1.x, y1, w0); a1.y = fma4(a1.y, y1, w1);
        a1.z = fma4(a1.z, y1, w2); a1.w = fma4(a1.w, y1, w3);
        a2.x = fma4(a2.x, y2, w0); a2.y = fma4(a2.y, y2, w1);
        a2.z = fma4(a2.z, y2, w2); a2.w = fma4(a2.w, y2, w3);
        a3.x = fma4(a3.x, y3, w0); a3.y = fma4(a3.y, y3, w1);
        a3.z = fma4(a3.z, y3, w2); a3.w = fma4(a3.w, y3, w3);
      }
      f4[F4_PRR + (kc * 4 + 0) * 65 + jq] = a0;
      f4[F4_PRR + (kc * 4 + 1) * 65 + jq] = a1;
      f4[F4_PRR + (kc * 4 + 2) * 65 + jq] = a2;
      f4[F4_PRR + (kc * 4 + 3) * 65 + jq] = a3;
    }
    __syncthreads();
    // ===== RNN reduce -> h' into ycP/ycQ
    if (tid < 256) {
      const int r = tid >> 6, jq = tid & 63;
      float4 v = bc4[jq];
#pragma unroll
      for (int kc = 0; kc < 8; ++kc)
        v = add4(v, f4[F4_PRR + (kc * 4 + r) * 65 + jq]);
      float4 hn = add4(f4[F4_HS + r * 64 + jq], tfast4(v));
      if (r < 2) f4[F4_YCP + r * 64 + jq] = hn;
      else       f4[F4_YCQ + (r - 2) * 64 + jq] = hn;
    }
    __syncthreads();

    // ===== eval pipeline: P leads, Q lags one sub-phase
#pragma unroll 1
    for (int e = 0; e < 16; ++e) {
      // A: L1part(P,e)  +  L2red(Q,e-1)  (+ state init at e==0)
      L1PART(F4_YCP, F4_PR1P);
      if (tid < 128) {
        if (e == 0) {
          hP = f4[F4_YCP + rxS * 64 + cqS];
          hQ = f4[F4_YCQ + rxS * 64 + cqS];
          acP = make_float4(0, 0, 0, 0); acQ = acP;
          scP = sm[SM_SCL + rxS];
          scQ = sm[SM_SCL + 2 + rxS];
        } else {
          L2RED(hQ, acQ, scQ, F4_PR2Q, F4_YCQ, 2 + rxS, e - 1);
        }
      }
      __syncthreads();
      // B: L1part(Q,e)  +  L1red(P)
      L1PART(F4_YCQ, F4_PR1Q);
      if (tid < 128) L1RED(F4_PR1P, F4_MIDP);
      __syncthreads();
      // C: L2part(P,e)  +  L1red(Q)
      L2PART(F4_MIDP, F4_PR2P);
      if (tid < 128) L1RED(F4_PR1Q, F4_MIDQ);
      __syncthreads();
      // D: L2part(Q,e)  +  L2red(P,e)
      L2PART(F4_MIDQ, F4_PR2Q);
      if (tid < 128) L2RED(hP, acP, scP, F4_PR2P, F4_YCP, 0 + rxS, e);
      __syncthreads();
    }
    // epilogue: L2red(Q,15) + stage next x/scl
    if (tid < 128) {
      L2RED(hQ, acQ, scQ, F4_PR2Q, F4_YCQ, 2 + rxS, 15);
    } else if (t < 99) {
      if (tid < 160) {
        int idx = tid - 128, r = idx >> 3, g = idx & 7;
        f4[F4_XS + idx] = xg4[((size_t)(b0 + r) * 100 + t + 1) * 8 + g];
      } else if (tid < 164) {
        int r = tid - 160;
        const float* dp = dt + ((size_t)(b0 + r) * 100 + t + 1) * 2;
        sm[SM_SCL + r] = (dp[1] - dp[0]) * (1.f / 24.f);
      }
    }
    __syncthreads();

    // ===== heads: partials (R4 verbatim shapes), both in one phase
    {
      const int cq = tid & 31, kc = tid >> 5;
      float4 c0 = make_float4(0, 0, 0, 0), c1 = c0, c2 = c0, c3 = c0;
#pragma unroll 2
      for (int g = 0; g < 4; ++g) {
        int kg = kc * 4 + g;
        float4 w0 = l1w4[kg * 128 + 4 * cq + 0];
        float4 w1 = l1w4[kg * 128 + 4 * cq + 1];
        float4 w2 = l1w4[kg * 128 + 4 * cq + 2];
        float4 w3 = l1w4[kg * 128 + 4 * cq + 3];
        float4 y0 = f4[F4_HS + kg],       y1 = f4[F4_HS + 64 + kg];
        float4 y2 = f4[F4_HS + 128 + kg], y3 = f4[F4_HS + 192 + kg];
        c0.x = fma4(c0.x, y0, w0); c0.y = fma4(c0.y, y0, w1);
        c0.z = fma4(c0.z, y0, w2); c0.w = fma4(c0.w, y0, w3);
        c1.x = fma4(c1.x, y1, w0); c1.y = fma4(c1.y, y1, w1);
        c1.z = fma4(c1.z, y1, w2); c1.w = fma4(c1.w, y1, w3);
        c2.x = fma4(c2.x, y2, w0); c2.y = fma4(c2.y, y2, w1);
        c2.z = fma4(c2.z, y2, w2); c2.w = fma4(c2.w, y2, w3);
        c3.x = fma4(c3.x, y3, w0); c3.y = fma4(c3.y, y3, w1);
        c3.z = fma4(c3.z, y3, w2); c3.w = fma4(c3.w, y3, w3);
      }
      f4[F4_PH1 + (kc * 4 + 0) * 33 + cq] = c0;
      f4[F4_PH1 + (kc * 4 + 1) * 33 + cq] = c1;
      f4[F4_PH1 + (kc * 4 + 2) * 33 + cq] = c2;
      f4[F4_PH1 + (kc * 4 + 3) * 33 + cq] = c3;
    }
    {
      const int cq = tid & 63, kc = tid >> 6;
      float4 d0 = make_float4(0, 0, 0, 0), d1 = d0, d2 = d0, d3 = d0;
#pragma unroll 2
      for (int g = 0; g < 8; ++g) {
        int kg = kc * 8 + g;
        float4 w0 = sw14[kg * 256 + 4 * cq + 0];
        float4 w1 = sw14[kg * 256 + 4 * cq + 1];
        float4 w2 = sw14[kg * 256 + 4 * cq + 2];
        float4 w3 = sw14[kg * 256 + 4 * cq + 3];
        float4 y0 = f4[F4_HS + kg],       y1 = f4[F4_HS + 64 + kg];
        float4 y2 = f4[F4_HS + 128 + kg], y3 = f4[F4_HS + 192 + kg];
        d0.x = fma4(d0.x, y0, w0); d0.y = fma4(d0.y, y0, w1);
        d0.z = fma4(d0.z, y0, w2); d0.w = fma4(d0.w, y0, w3);
        d1.x = fma4(d1.x, y1, w0); d1.y = fma4(d1.y, y1, w1);
        d1.z = fma4(d1.z, y1, w2); d1.w = fma4(d1.w, y1, w3);
        d2.x = fma4(d2.x, y2, w0); d2.y = fma4(d2.y, y2, w1);
        d2.z = fma4(d2.z, y2, w2); d2.w = fma4(d2.w, y2, w3);
        d3.x = fma4(d3.x, y3, w0); d3.y = fma4(d3.y, y3, w1);
        d3.z = fma4(d3.z, y3, w2); d3.w = fma4(d3.w, y3, w3);
      }
      f4[F4_PH2 + (kc * 4 + 0) * 65 + cq] = d0;
      f4[F4_PH2 + (kc * 4 + 1) * 65 + cq] = d1;
      f4[F4_PH2 + (kc * 4 + 2) * 65 + cq] = d2;
      f4[F4_PH2 + (kc * 4 + 3) * 65 + cq] = d3;
    }
    __syncthreads();
    // ===== head reduces
    if (tid < 128) {
      const int r = tid >> 5, cq = tid & 31;
      float4 v = l1b4[cq];
#pragma unroll
      for (int kc = 0; kc < 16; ++kc)
        v = add4(v, f4[F4_PH1 + (kc * 4 + r) * 33 + cq]);
      f4[F4_L1O + r * 32 + cq] =
          make_float4(fmaxf(v.x, 0.f), fmaxf(v.y, 0.f),
                      fmaxf(v.z, 0.f), fmaxf(v.w, 0.f));
    } else if (tid < 384) {
      const int t2 = tid - 128;
      const int r = t2 >> 6, cq = t2 & 63;
      float4 v = sb14[cq];
#pragma unroll
      for (int kc = 0; kc < 8; ++kc)
        v = add4(v, f4[F4_PH2 + (kc * 4 + r) * 65 + cq]);
      f4[F4_SG + r * 64 + cq] = tfast4(v);
    }
    __syncthreads();
    // ===== final dots: waves 0-3 mu rows, 4-7 sig rows
    if (wv < 4) {
      float pm = 0.f;
      if (ln < 32) {
        float4 l = f4[F4_L1O + wv * 32 + ln];
        float4 w = muw4[ln];
        pm = l.x * w.x + l.y * w.y + l.z * w.z + l.w * w.w;
      }
#pragma unroll
      for (int off = 32; off > 0; off >>= 1) pm += __shfl_down(pm, off);
      if (ln == 0) out[(size_t)(b0 + wv) * 100 + t] = pm + mubv;
    } else {
      const int r = wv - 4;
      float4 sv = f4[F4_SG + r * 64 + ln];
      float4 w = sw24[ln];
      float ps = sv.x * w.x + sv.y * w.y + sv.z * w.z + sv.w * w.w;
#pragma unroll
      for (int off = 32; off > 0; off >>= 1) ps += __shfl_down(ps, off);
      if (ln == 0) {
        float z = ps + sb2v;
        float sp = fmaxf(z, 0.f) + log1pf(expf(-fabsf(z)));
        out[(size_t)102400 + (size_t)(b0 + r) * 100 + t] = sp;
      }
    }
    __syncthreads();   // l1o/sg reads done before next step's prR writes
  }
}

extern "C" void kernel_launch(void* const* d_in, const int* in_sizes, int n_in,
                              void* d_out, int out_size, void* d_ws, size_t ws_size,
                              hipStream_t stream) {
  const float* dt  = (const float*)d_in[0];
  const float* x   = (const float*)d_in[1];
  const float* Wih = (const float*)d_in[2];
  const float* bih = (const float*)d_in[3];
  const float* Whh = (const float*)d_in[4];
  const float* bhh = (const float*)d_in[5];
  const float* ow1 = (const float*)d_in[6];
  const float* ob1 = (const float*)d_in[7];
  const float* ow2 = (const float*)d_in[8];
  const float* ob2 = (const float*)d_in[9];
  const float* l1w = (const float*)d_in[10];
  const float* l1b = (const float*)d_in[11];
  const float* muw = (const float*)d_in[12];
  const float* mub = (const float*)d_in[13];
  const float* sw1 = (const float*)d_in[14];
  const float* sb1 = (const float*)d_in[15];
  const float* sw2 = (const float*)d_in[16];
  const float* sb2 = (const float*)d_in[17];
  float* ws  = (float*)d_ws;
  float* out = (float*)d_out;

  hipFuncSetAttribute((const void*)odernn_main,
                      hipFuncAttributeMaxDynamicSharedMemorySize, SMEM_BYTES);

  prep_w<<<WS_TOT / 256, 256, 0, stream>>>(Wih, Whh, l1w, sw1, ws);
  odernn_main<<<256, NT, SMEM_BYTES, stream>>>(dt, x, bih, bhh, ow1, ob1, ow2, ob2,
                                               l1b, muw, mub, sb1, sw2, sb2, ws, out);
}

// Round 12
// 3322.730 us; speedup vs baseline: 1.3154x; 1.2270x over previous
//
#include <hip/hip_runtime.h>
#include <math.h>

// ODE-RNN forward: B=1024, T=100, D=32, H=256, MID=50 (pad 52), RK4x4.
// Round 12: wave-specialized dual pipeline. Block = 4 waves (1/SIMD), 4 rows.
// A-waves hold ode_w1 (208 VGPR), B-waves hold ode_w2 (208 VGPR); weights
// re-loaded from LDS once per step (dead during RNN/heads -> no spill).
// 33 thin eval phases, each = L1(pair X, A-waves) || L2(pair Y, B-waves).
// Reductions: R8-verified DPP red16 (pure VALU). RNN/heads: R4 structure.

#define NT 256

// ---- ws layout (floats): R4-proven prep ----
#define WS_WCAT 0        // [72 g][256 j][4 c]
#define WS_L1P  73728    // [64 g][128 j][4 c]
#define WS_SW1  106496   // [64 g][256 j][4 c]
#define WS_TOT  172032

// ---- LDS layout (f4 offsets) ----
#define F4_YC   0        // [4 rows][64]
#define F4_MID  256      // f32 [4 rows][64]
#define F4_PRR  320      // RNN partials 16 slabs x 65  (alias PH1)
#define F4_PH1  320      // mu-head partials 32 slabs x 33 (=1056)
#define F4_PH2  1376     // sig-head partials 16 slabs x 65 (=1040)
#define F4_XS   2416     // [4 rows][8]
#define F4_L1O  2448     // [4][32]
#define F4_SG   2576     // [4][64]
#define F4_W1   2832     // ode_w1 staged: [52 j][4 f][16 kc]  (3328)
#define F4_W2   6160     // ode_w2 staged: [4 C][13 g][64 ln]  (3328)
#define F4_END  9488
#define SM_BC   (F4_END*4)        // 256
#define SM_OB2  (SM_BC+256)       // 256
#define SM_L1B  (SM_OB2+256)      // 128
#define SM_SB1  (SM_L1B+128)      // 256
#define SM_MUW  (SM_SB1+256)      // 128
#define SM_SW2  (SM_MUW+128)      // 256
#define SM_SCL  (SM_SW2+256)      // 4
#define SM_TOTF (SM_SCL+4)
#define SMEM_BYTES (SM_TOTF*4)

__device__ __forceinline__ float fma4(float a, float4 y, float4 w) {
  a = fmaf(y.x, w.x, a); a = fmaf(y.y, w.y, a);
  a = fmaf(y.z, w.z, a); a = fmaf(y.w, w.w, a);
  return a;
}
__device__ __forceinline__ float4 add4(float4 a, float4 b) {
  return make_float4(a.x+b.x, a.y+b.y, a.z+b.z, a.w+b.w);
}
__device__ __forceinline__ float4 axpy4(float a, float4 xv, float4 yv) {
  return make_float4(fmaf(a,xv.x,yv.x), fmaf(a,xv.y,yv.y),
                     fmaf(a,xv.z,yv.z), fmaf(a,xv.w,yv.w));
}
__device__ __forceinline__ float4 muls4(float4 v, float s) {
  return make_float4(v.x*s, v.y*s, v.z*s, v.w*s);
}
__device__ __forceinline__ float tfast(float x) {
  float ax = fabsf(x);
  float e  = __expf(-2.f * ax);
  float t  = (1.f - e) * __builtin_amdgcn_rcpf(1.f + e);
  return copysignf(t, x);
}
__device__ __forceinline__ float4 tfast4(float4 v) {
  return make_float4(tfast(v.x), tfast(v.y), tfast(v.z), tfast(v.w));
}
// DPP butterfly adds (HW-verified R8). After red16, every lane of each
// aligned 16-lane group holds the group sum. Pure VALU.
template <int CTRL>
__device__ __forceinline__ float dpp_add(float v) {
  int s = __builtin_amdgcn_update_dpp(0, __float_as_int(v), CTRL, 0xF, 0xF, true);
  return v + __int_as_float(s);
}
__device__ __forceinline__ float red16(float v) {
  return dpp_add<0xB1>(dpp_add<0x4E>(dpp_add<0x141>(dpp_add<0x140>(v))));
}

__global__ void prep_w(const float* __restrict__ Wih, const float* __restrict__ Whh,
                       const float* __restrict__ l1w, const float* __restrict__ sw1,
                       float* __restrict__ ws) {
  int i = blockIdx.x * 256 + threadIdx.x;
  if (i < 73728) {                       // Wcat4
    int g = i >> 10, rem = i & 1023, j = rem >> 2, c = rem & 3;
    int k = 4 * g + c;
    ws[i] = (k < 32) ? Wih[j * 32 + k] : Whh[j * 256 + (k - 32)];
  } else if (i < 106496) {               // l1p4
    int t = i - 73728;
    int g = t >> 9, rem = t & 511, j = rem >> 2, c = rem & 3;
    ws[i] = l1w[j * 256 + 4 * g + c];
  } else if (i < WS_TOT) {               // sw1p4
    int t = i - 106496;
    int g = t >> 10, rem = t & 1023, j = rem >> 2, c = rem & 3;
    ws[i] = sw1[j * 256 + 4 * g + c];
  }
}

__global__ __attribute__((amdgpu_flat_work_group_size(NT, NT)))
void odernn_main(const float* __restrict__ dt,
                 const float* __restrict__ x,
                 const float* __restrict__ bih,
                 const float* __restrict__ bhh,
                 const float* __restrict__ ow1,
                 const float* __restrict__ ob1g,
                 const float* __restrict__ ow2,
                 const float* __restrict__ ob2g,
                 const float* __restrict__ l1bg,
                 const float* __restrict__ muwg,
                 const float* __restrict__ mubg,
                 const float* __restrict__ sb1g,
                 const float* __restrict__ sw2g,
                 const float* __restrict__ sb2g,
                 const float* __restrict__ ws,
                 float* __restrict__ out) {
  extern __shared__ __align__(16) float sm[];
  float4* f4 = (float4*)sm;
  float* midS = sm + F4_MID * 4;                 // f32 [4][64]
  const int tid = threadIdx.x;
  const int wv = tid >> 6, ln = tid & 63;
  const int b0 = blockIdx.x * 4;
  const bool isA = (wv & 1) == 0;
  const int ra = (wv >> 1) * 2, rb = ra + 1;     // pipeline rows

  const float4* wcat4 = (const float4*)(ws + WS_WCAT);
  const float4* l1w4  = (const float4*)(ws + WS_L1P);
  const float4* sw14  = (const float4*)(ws + WS_SW1);
  const float4* xg4   = (const float4*)x;

  // ---------- prologue: stage weights to LDS, biases, x, scl, h=0 ----------
  for (int i = tid; i < 3328; i += NT) {         // w1: [j][f][kc]
    int j = i >> 6, rem = i & 63, f = rem >> 4, kq = rem & 15;
    float4 v = make_float4(0.f, 0.f, 0.f, 0.f);
    if (j < 50) v = *(const float4*)&ow1[j * 256 + kq * 16 + 4 * f];
    f4[F4_W1 + (j * 4 + f) * 16 + kq] = v;
  }
  for (int i = tid; i < 3328; i += NT) {         // w2: [C][g][ln]
    int cg = i >> 6, lq = i & 63;
    int C = cg / 13, g = cg - C * 13;
    int col = 4 * lq + C;
    float t0 = (4*g+0 < 50) ? ow2[col*50 + 4*g+0] : 0.f;
    float t1 = (4*g+1 < 50) ? ow2[col*50 + 4*g+1] : 0.f;
    float t2 = (4*g+2 < 50) ? ow2[col*50 + 4*g+2] : 0.f;
    float t3 = (4*g+3 < 50) ? ow2[col*50 + 4*g+3] : 0.f;
    f4[F4_W2 + i] = make_float4(t0, t1, t2, t3);
  }
  sm[SM_BC + tid]  = bih[tid] + bhh[tid];
  sm[SM_OB2 + tid] = ob2g[tid];
  sm[SM_SB1 + tid] = sb1g[tid];
  sm[SM_SW2 + tid] = sw2g[tid];
  if (tid < 128) { sm[SM_L1B + tid] = l1bg[tid]; sm[SM_MUW + tid] = muwg[tid]; }
  f4[F4_YC + tid] = make_float4(0.f, 0.f, 0.f, 0.f);   // h0 = 0 (4x64)
  if (tid < 32) {
    int r = tid >> 3, g = tid & 7;
    f4[F4_XS + tid] = xg4[((size_t)(b0 + r) * 100) * 8 + g];
  } else if (tid < 36) {
    int r = tid - 32;
    const float* dp = dt + ((size_t)(b0 + r) * 100) * 2;
    sm[SM_SCL + r] = (dp[1] - dp[0]) * (1.f / 24.f);
  }
  __syncthreads();

  const float mubv = mubg[0], sb2v = sb2g[0];
  const float4* bc4  = (const float4*)(sm + SM_BC);
  const float4* l1b4 = (const float4*)(sm + SM_L1B);
  const float4* sb14 = (const float4*)(sm + SM_SB1);
  const float4* muw4 = (const float4*)(sm + SM_MUW);
  const float4* sw24 = (const float4*)(sm + SM_SW2);

  // ---------- shared phase lambdas (identical code in both branches) -------
  auto RNNPART = [&]() {
    const int jq = tid & 63, kc = tid >> 6;      // kc 0..3, 18 g-chunks each
    float4 a0 = make_float4(0,0,0,0), a1 = a0, a2 = a0, a3 = a0;
#pragma unroll 2
    for (int gg = 0; gg < 18; ++gg) {
      int g = kc * 18 + gg;
      float4 w0 = wcat4[g * 256 + 4 * jq + 0];
      float4 w1 = wcat4[g * 256 + 4 * jq + 1];
      float4 w2 = wcat4[g * 256 + 4 * jq + 2];
      float4 w3 = wcat4[g * 256 + 4 * jq + 3];
      float4 y0 = (g < 8) ? f4[F4_XS + g]      : f4[F4_YC + (g - 8)];
      float4 y1 = (g < 8) ? f4[F4_XS + 8 + g]  : f4[F4_YC + 64 + (g - 8)];
      float4 y2 = (g < 8) ? f4[F4_XS + 16 + g] : f4[F4_YC + 128 + (g - 8)];
      float4 y3 = (g < 8) ? f4[F4_XS + 24 + g] : f4[F4_YC + 192 + (g - 8)];
      a0.x = fma4(a0.x, y0, w0); a0.y = fma4(a0.y, y0, w1);
      a0.z = fma4(a0.z, y0, w2); a0.w = fma4(a0.w, y0, w3);
      a1.x = fma4(a1.x, y1, w0); a1.y = fma4(a1.y, y1, w1);
      a1.z = fma4(a1.z, y1, w2); a1.w = fma4(a1.w, y1, w3);
      a2.x = fma4(a2.x, y2, w0); a2.y = fma4(a2.y, y2, w1);
      a2.z = fma4(a2.z, y2, w2); a2.w = fma4(a2.w, y2, w3);
      a3.x = fma4(a3.x, y3, w0); a3.y = fma4(a3.y, y3, w1);
      a3.z = fma4(a3.z, y3, w2); a3.w = fma4(a3.w, y3, w3);
    }
    f4[F4_PRR + (kc * 4 + 0) * 65 + jq] = a0;
    f4[F4_PRR + (kc * 4 + 1) * 65 + jq] = a1;
    f4[F4_PRR + (kc * 4 + 2) * 65 + jq] = a2;
    f4[F4_PRR + (kc * 4 + 3) * 65 + jq] = a3;
  };
  auto RNNRED = [&]() {
    const int r = tid >> 6, jq = tid & 63;
    float4 v = bc4[jq];
#pragma unroll
    for (int kc = 0; kc < 4; ++kc)
      v = add4(v, f4[F4_PRR + (kc * 4 + r) * 65 + jq]);
    float4 hold = f4[F4_YC + r * 64 + jq];
    f4[F4_YC + r * 64 + jq] = add4(hold, tfast4(v));
  };
  auto HEADSPART = [&]() {
    {  // mu-l1 partials: (cq 32, kc 8)
      const int cq = tid & 31, kc = tid >> 5;
      float4 c0 = make_float4(0,0,0,0), c1 = c0, c2 = c0, c3 = c0;
#pragma unroll 2
      for (int g = 0; g < 8; ++g) {
        int kg = kc * 8 + g;
        float4 w0 = l1w4[kg * 128 + 4 * cq + 0];
        float4 w1 = l1w4[kg * 128 + 4 * cq + 1];
        float4 w2 = l1w4[kg * 128 + 4 * cq + 2];
        float4 w3 = l1w4[kg * 128 + 4 * cq + 3];
        float4 y0 = f4[F4_YC + kg],       y1 = f4[F4_YC + 64 + kg];
        float4 y2 = f4[F4_YC + 128 + kg], y3 = f4[F4_YC + 192 + kg];
        c0.x = fma4(c0.x, y0, w0); c0.y = fma4(c0.y, y0, w1);
        c0.z = fma4(c0.z, y0, w2); c0.w = fma4(c0.w, y0, w3);
        c1.x = fma4(c1.x, y1, w0); c1.y = fma4(c1.y, y1, w1);
        c1.z = fma4(c1.z, y1, w2); c1.w = fma4(c1.w, y1, w3);
        c2.x = fma4(c2.x, y2, w0); c2.y = fma4(c2.y, y2, w1);
        c2.z = fma4(c2.z, y2, w2); c2.w = fma4(c2.w, y2, w3);
        c3.x = fma4(c3.x, y3, w0); c3.y = fma4(c3.y, y3, w1);
        c3.z = fma4(c3.z, y3, w2); c3.w = fma4(c3.w, y3, w3);
      }
      f4[F4_PH1 + (kc * 4 + 0) * 33 + cq] = c0;
      f4[F4_PH1 + (kc * 4 + 1) * 33 + cq] = c1;
      f4[F4_PH1 + (kc * 4 + 2) * 33 + cq] = c2;
      f4[F4_PH1 + (kc * 4 + 3) * 33 + cq] = c3;
    }
    {  // sig-l1 partials: (cq 64, kc 4)
      const int cq = tid & 63, kc = tid >> 6;
      float4 d0 = make_float4(0,0,0,0), d1 = d0, d2 = d0, d3 = d0;
#pragma unroll 2
      for (int g = 0; g < 16; ++g) {
        int kg = kc * 16 + g;
        float4 w0 = sw14[kg * 256 + 4 * cq + 0];
        float4 w1 = sw14[kg * 256 + 4 * cq + 1];
        float4 w2 = sw14[kg * 256 + 4 * cq + 2];
        float4 w3 = sw14[kg * 256 + 4 * cq + 3];
        float4 y0 = f4[F4_YC + kg],       y1 = f4[F4_YC + 64 + kg];
        float4 y2 = f4[F4_YC + 128 + kg], y3 = f4[F4_YC + 192 + kg];
        d0.x = fma4(d0.x, y0, w0); d0.y = fma4(d0.y, y0, w1);
        d0.z = fma4(d0.z, y0, w2); d0.w = fma4(d0.w, y0, w3);
        d1.x = fma4(d1.x, y1, w0); d1.y = fma4(d1.y, y1, w1);
        d1.z = fma4(d1.z, y1, w2); d1.w = fma4(d1.w, y1, w3);
        d2.x = fma4(d2.x, y2, w0); d2.y = fma4(d2.y, y2, w1);
        d2.z = fma4(d2.z, y2, w2); d2.w = fma4(d2.w, y2, w3);
        d3.x = fma4(d3.x, y3, w0); d3.y = fma4(d3.y, y3, w1);
        d3.z = fma4(d3.z, y3, w2); d3.w = fma4(d3.w, y3, w3);
      }
      f4[F4_PH2 + (kc * 4 + 0) * 65 + cq] = d0;
      f4[F4_PH2 + (kc * 4 + 1) * 65 + cq] = d1;
      f4[F4_PH2 + (kc * 4 + 2) * 65 + cq] = d2;
      f4[F4_PH2 + (kc * 4 + 3) * 65 + cq] = d3;
    }
  };
  auto HEADSRED = [&]() {
    if (tid < 128) {
      int r = tid >> 5, cq = tid & 31;
      float4 v = l1b4[cq];
#pragma unroll
      for (int kc = 0; kc < 8; ++kc)
        v = add4(v, f4[F4_PH1 + (kc * 4 + r) * 33 + cq]);
      f4[F4_L1O + r * 32 + cq] =
          make_float4(fmaxf(v.x, 0.f), fmaxf(v.y, 0.f),
                      fmaxf(v.z, 0.f), fmaxf(v.w, 0.f));
    }
    {
      int r = tid >> 6, cq = tid & 63;
      float4 v = sb14[cq];
#pragma unroll
      for (int kc = 0; kc < 4; ++kc)
        v = add4(v, f4[F4_PH2 + (kc * 4 + r) * 65 + cq]);
      f4[F4_SG + r * 64 + cq] = tfast4(v);
    }
  };
  auto DOTS = [&](int t) {
    float pm = 0.f;
    if (ln < 32) {
      float4 l = f4[F4_L1O + wv * 32 + ln];
      float4 w = muw4[ln];
      pm = l.x * w.x + l.y * w.y + l.z * w.z + l.w * w.w;
    }
#pragma unroll
    for (int off = 32; off > 0; off >>= 1) pm += __shfl_down(pm, off);
    if (ln == 0) out[(size_t)(b0 + wv) * 100 + t] = pm + mubv;
    float4 sv = f4[F4_SG + wv * 64 + ln];
    float4 w2v = sw24[ln];
    float ps = sv.x * w2v.x + sv.y * w2v.y + sv.z * w2v.z + sv.w * w2v.w;
#pragma unroll
    for (int off = 32; off > 0; off >>= 1) ps += __shfl_down(ps, off);
    if (ln == 0) {
      float z = ps + sb2v;
      float sp = fmaxf(z, 0.f) + log1pf(expf(-fabsf(z)));
      out[(size_t)102400 + (size_t)(b0 + wv) * 100 + t] = sp;
    }
  };

  if (isA) {
    // =================== A side: ODE layer-1 for rows ra, rb ===============
    const int qA = ln >> 4, kcA = ln & 15;
    float4 w1r[13][4];
    float ob1A = 0.f;
    {
      int jb = qA * 13 + kcA;
      if (kcA < 13 && jb < 50) ob1A = ob1g[jb];
    }
    auto L1 = [&](int row) {
      const float4* ycr = f4 + F4_YC + row * 64 + kcA * 4;
      float4 y0 = ycr[0], y1 = ycr[1], y2 = ycr[2], y3 = ycr[3];
      float p[13];
#pragma unroll
      for (int jj = 0; jj < 13; ++jj) {
        float s = 0.f;
        s = fma4(s, y0, w1r[jj][0]); s = fma4(s, y1, w1r[jj][1]);
        s = fma4(s, y2, w1r[jj][2]); s = fma4(s, y3, w1r[jj][3]);
        p[jj] = s;
      }
#pragma unroll
      for (int jj = 0; jj < 13; ++jj) p[jj] = red16(p[jj]);
      if (kcA < 13) {
        float v = p[0];
#pragma unroll
        for (int jj = 1; jj < 13; ++jj) v = (kcA == jj) ? p[jj] : v;
        midS[row * 64 + qA * 13 + kcA] = tfast(v + ob1A);
      }
    };

    for (int t = 0; t < 100; ++t) {
      RNNPART();  __syncthreads();
      RNNRED();   __syncthreads();
      // reload w1 from LDS (dead during RNN/heads -> no spill)
#pragma unroll
      for (int jj = 0; jj < 13; ++jj)
#pragma unroll
        for (int f = 0; f < 4; ++f)
          w1r[jj][f] = f4[F4_W1 + ((qA * 13 + jj) * 4 + f) * 16 + kcA];
#pragma unroll 1
      for (int ph = 0; ph <= 32; ++ph) {
        if (ph < 32) {
          L1(ra + (ph & 1));
        } else if (t < 99 && wv == 0) {          // stage next x / scl
          if (ln < 32) {
            int r = ln >> 3, g = ln & 7;
            f4[F4_XS + ln] = xg4[((size_t)(b0 + r) * 100 + t + 1) * 8 + g];
          } else if (ln < 36) {
            int r = ln - 32;
            const float* dp = dt + ((size_t)(b0 + r) * 100 + t + 1) * 2;
            sm[SM_SCL + r] = (dp[1] - dp[0]) * (1.f / 24.f);
          }
        }
        __syncthreads();
      }
      HEADSPART(); __syncthreads();
      HEADSRED();  __syncthreads();
      DOTS(t);     __syncthreads();
    }
  } else {
    // ============ B side: ODE layer-2 + RK4 state for rows ra, rb ==========
    float4 w2c0[13], w2c1[13], w2c2[13], w2c3[13];
    float4 hA, hB, acA, acB;
    float sclA = 0.f, sclB = 0.f;
    auto L2 = [&](int row, int e, float4& h, float4& ac, float sc) {
      const float4* mr = (const float4*)(midS + row * 64);
      float bx = 0.f, by = 0.f, bz = 0.f, bw = 0.f;
#define L2STEP(mv, g) bx = fma4(bx, mv, w2c0[g]); by = fma4(by, mv, w2c1[g]); \
                      bz = fma4(bz, mv, w2c2[g]); bw = fma4(bw, mv, w2c3[g]);
      {
        float4 a0 = mr[0], a1 = mr[1], a2 = mr[2], a3 = mr[3], a4 = mr[4];
        L2STEP(a0, 0) L2STEP(a1, 1) L2STEP(a2, 2) L2STEP(a3, 3) L2STEP(a4, 4)
      }
      {
        float4 a0 = mr[5], a1 = mr[6], a2 = mr[7], a3 = mr[8];
        L2STEP(a0, 5) L2STEP(a1, 6) L2STEP(a2, 7) L2STEP(a3, 8)
      }
      {
        float4 a0 = mr[9], a1 = mr[10], a2 = mr[11], a3 = mr[12];
        L2STEP(a0, 9) L2STEP(a1, 10) L2STEP(a2, 11) L2STEP(a3, 12)
      }
#undef L2STEP
      float4 ob2v = ((const float4*)(sm + SM_OB2))[ln];
      float4 kv = muls4(add4(make_float4(bx, by, bz, bw), ob2v), sc);
      const int s = e & 3;
      float4 ycw;
      if (s == 0)      { ac = kv;                 ycw = axpy4(0.125f, kv, h); }
      else if (s == 1) { ac = axpy4(2.f, kv, ac); ycw = axpy4(0.125f, kv, h); }
      else if (s == 2) { ac = axpy4(2.f, kv, ac); ycw = axpy4(0.25f,  kv, h); }
      else             { h = axpy4(0.25f / 6.f, add4(ac, kv), h); ycw = h; }
      f4[F4_YC + row * 64 + ln] = ycw;
    };

    for (int t = 0; t < 100; ++t) {
      RNNPART();  __syncthreads();
      RNNRED();   __syncthreads();
      // reload w2 from LDS
#pragma unroll
      for (int g = 0; g < 13; ++g) {
        w2c0[g] = f4[F4_W2 + (0 * 13 + g) * 64 + ln];
        w2c1[g] = f4[F4_W2 + (1 * 13 + g) * 64 + ln];
        w2c2[g] = f4[F4_W2 + (2 * 13 + g) * 64 + ln];
        w2c3[g] = f4[F4_W2 + (3 * 13 + g) * 64 + ln];
      }
#pragma unroll 1
      for (int ph = 0; ph <= 32; ++ph) {
        if (ph == 0) {
          hA = f4[F4_YC + ra * 64 + ln];
          hB = f4[F4_YC + rb * 64 + ln];
          acA = make_float4(0.f, 0.f, 0.f, 0.f); acB = acA;
          sclA = sm[SM_SCL + ra]; sclB = sm[SM_SCL + rb];
        } else if (ph & 1) {
          L2(ra, (ph - 1) >> 1, hA, acA, sclA);
        } else {
          L2(rb, (ph - 2) >> 1, hB, acB, sclB);
        }
        __syncthreads();
      }
      HEADSPART(); __syncthreads();
      HEADSRED();  __syncthreads();
      DOTS(t);     __syncthreads();
    }
  }
}

extern "C" void kernel_launch(void* const* d_in, const int* in_sizes, int n_in,
                              void* d_out, int out_size, void* d_ws, size_t ws_size,
                              hipStream_t stream) {
  const float* dt  = (const float*)d_in[0];
  const float* x   = (const float*)d_in[1];
  const float* Wih = (const float*)d_in[2];
  const float* bih = (const float*)d_in[3];
  const float* Whh = (const float*)d_in[4];
  const float* bhh = (const float*)d_in[5];
  const float* ow1 = (const float*)d_in[6];
  const float* ob1 = (const float*)d_in[7];
  const float* ow2 = (const float*)d_in[8];
  const float* ob2 = (const float*)d_in[9];
  const float* l1w = (const float*)d_in[10];
  const float* l1b = (const float*)d_in[11];
  const float* muw = (const float*)d_in[12];
  const float* mub = (const float*)d_in[13];
  const float* sw1 = (const float*)d_in[14];
  const float* sb1 = (const float*)d_in[15];
  const float* sw2 = (const float*)d_in[16];
  const float* sb2 = (const float*)d_in[17];
  float* ws  = (float*)d_ws;
  float* out = (float*)d_out;

  hipFuncSetAttribute((const void*)odernn_main,
                      hipFuncAttributeMaxDynamicSharedMemorySize, SMEM_BYTES);

  prep_w<<<WS_TOT / 256, 256, 0, stream>>>(Wih, Whh, l1w, sw1, ws);
  odernn_main<<<256, NT, SMEM_BYTES, stream>>>(dt, x, bih, bhh, ow1, ob1, ow2, ob2,
                                               l1b, muw, mub, sb1, sw2, sb2, ws, out);
}